// Round 7
// baseline (214.116 us; speedup 1.0000x reference)
//
#include <hip/hip_runtime.h>
#include <hip/hip_bf16.h>

// Problem constants
#define KCODES 2048
#define DIM 256
#define TLEN 2048
#define NB 16
#define NROWS (NB * TLEN)          // 32768 rows (b*t)
#define NELEM (NB * DIM * TLEN)    // 8388608 elements of x / quant
#define LOSS_OFF NELEM
#define IDX_OFF (NELEM + 2)

// Margin in the a = (bf16 dot) domain. s = xsq - 2a + esq; argmin s == argmax of
// (a - esq/2). Filter on a alone with margin covering: 2*bf16-err (s-domain 3e-3
// proven in R8 => a-domain 1.5e-3) + esq spread/2 (~3e-5) + u16-trunc of stored
// maxima (~1.2e-4). 1.8e-3 > sum => candidate superset provably contains argmin.
// (Scheme proven passing in R5/R6 with absmax 0.0.)
#define AMARGIN 1.8e-3f

// Candidate list capacity per row. Retrospective global-max qualification gives
// E[#cands] ~ 3-10; overflow still handled exactly by full-scan fallback.
#define CCAP 48

// ws layout (bytes) — total ~8.0 MB
#define OFF_XSQ   0ull                       // 131072 (fallback path only)
#define OFF_ESQ   131072ull                  // 8192
#define OFF_KEYS  139264ull                  // 262144
#define OFF_BSUM  401408ull                  // 131072
#define OFF_EHI   532480ull                  // 1048576
#define OFF_CCNT  1581056ull                 // 131072
#define OFF_CLIST 1712128ull                 // 32768*48*4 = 6291456
#define WS_NEED   8003584ull

typedef __bf16 bf16x8 __attribute__((ext_vector_type(8)));
typedef float  f32x4  __attribute__((ext_vector_type(4)));
typedef int    i32x4  __attribute__((ext_vector_type(4)));

__device__ __forceinline__ float sq_rn(float v) { return __fmul_rn(v, v); }

// order-preserving float<->u32 encoding (uint order == float order)
__device__ __forceinline__ unsigned encf(float f) {
    unsigned u = __float_as_uint(f);
    return (u & 0x80000000u) ? ~u : (u | 0x80000000u);
}
__device__ __forceinline__ float decf(unsigned k) {
    return __uint_as_float((k & 0x80000000u) ? (k & 0x7FFFFFFFu) : ~k);
}

// ---- x_sq: numpy pairwise sum (fallback path only)
__global__ __launch_bounds__(256) void xsq_kernel(const float* __restrict__ x,
                                                  float* __restrict__ xsq) {
    int m = blockIdx.x * 256 + threadIdx.x;
    int b = m >> 11, t = m & (TLEN - 1);
    const float* p = x + (size_t)b * DIM * TLEN + t;
    float h[2];
#pragma unroll
    for (int half = 0; half < 2; ++half) {
        int c0 = half * 128;
        float r[8];
#pragma unroll
        for (int j = 0; j < 8; ++j) r[j] = sq_rn(p[(size_t)(c0 + j) * TLEN]);
        for (int i = 8; i < 128; i += 8) {
#pragma unroll
            for (int j = 0; j < 8; ++j)
                r[j] = __fadd_rn(r[j], sq_rn(p[(size_t)(c0 + i + j) * TLEN]));
        }
        h[half] = __fadd_rn(__fadd_rn(__fadd_rn(r[0], r[1]), __fadd_rn(r[2], r[3])),
                            __fadd_rn(__fadd_rn(r[4], r[5]), __fadd_rn(r[6], r[7])));
    }
    xsq[m] = __fadd_rn(h[0], h[1]);
}

// ---- esq standalone (fallback path only)
__global__ __launch_bounds__(256) void esq_kernel(const float* __restrict__ cb,
                                                  float* __restrict__ esq) {
    int k = blockIdx.x * 256 + threadIdx.x;
    const float* p = cb + (size_t)k * DIM;
    float h[2];
#pragma unroll
    for (int half = 0; half < 2; ++half) {
        int c0 = half * 128;
        float r[8];
#pragma unroll
        for (int j = 0; j < 8; ++j) r[j] = sq_rn(p[c0 + j]);
        for (int i = 8; i < 128; i += 8) {
#pragma unroll
            for (int j = 0; j < 8; ++j)
                r[j] = __fadd_rn(r[j], sq_rn(p[c0 + i + j]));
        }
        h[half] = __fadd_rn(__fadd_rn(__fadd_rn(r[0], r[1]), __fadd_rn(r[2], r[3])),
                            __fadd_rn(__fadd_rn(r[4], r[5]), __fadd_rn(r[6], r[7])));
    }
    esq[k] = __fadd_rn(h[0], h[1]);
}

// ---- fused prep: cb -> Ehi (bf16) + esq (exact np pairwise chain, bit-identical)
__global__ __launch_bounds__(256) void prep_e_kernel(const float* __restrict__ cb,
                                                     __hip_bfloat16* __restrict__ Ehi,
                                                     float* __restrict__ esq) {
    int tid = threadIdx.x;
    int w = tid >> 6, lane = tid & 63;
    int k = (blockIdx.x << 2) + w;          // code row
    const float* p = cb + (size_t)k * DIM;

    float4 v = *reinterpret_cast<const float4*>(p + (lane << 2));
    alignas(8) __hip_bfloat16 h4[4];
    h4[0] = __float2bfloat16(v.x); h4[1] = __float2bfloat16(v.y);
    h4[2] = __float2bfloat16(v.z); h4[3] = __float2bfloat16(v.w);
    *reinterpret_cast<int2*>(Ehi + (size_t)k * DIM + (lane << 2)) = *reinterpret_cast<int2*>(h4);

    if (lane < 16) {
        int c0 = (lane >> 3) << 7, j = lane & 7;
        float r = sq_rn(p[c0 + j]);
        for (int i = 8; i < 128; i += 8)
            r = __fadd_rn(r, sq_rn(p[c0 + i + j]));
        float a  = __fadd_rn(r,  __shfl_xor(r, 1, 16));
        float b2 = __fadd_rn(a,  __shfl_xor(a, 2, 16));
        float h  = __fadd_rn(b2, __shfl_xor(b2, 4, 16));
        float tot = __fadd_rn(h, __shfl_xor(h, 8, 16));   // h0 + h1, own-first
        if (lane == 0) esq[k] = tot;
    }
}

// ---- stage one [64 codes][128 k] bf16 chunk (16KB) of Ehi into LDS,
// COOPERATIVELY (all 256 threads). chunk s: code tile nt = s>>1, k-half = s&1.
// LDS linear [code][k] (128 elems = 256 B per row); XOR-swizzle applied by
// pre-swizzling the per-lane GLOBAL source 16B-slot (slot ^= row&7), read side
// applies the same XOR. One gload_lds = 1 KB = 4 code rows.
__device__ __forceinline__ void stage_chunk(const __hip_bfloat16* __restrict__ Ehi,
                                            __hip_bfloat16* dst,
                                            int s, int w, int lane) {
    int n0 = (s >> 1) << 6, k0 = (s & 1) << 7;
    int rlo = lane >> 4;                   // row within 4-row group
    int slot = lane & 15;                  // 16B slot within 256B row
#pragma unroll
    for (int j = 0; j < 4; ++j) {
        int row = (((w << 2) + j) << 2);   // uniform per (w, j)
        int gr = row + rlo;
        int scol = ((slot ^ (gr & 7)) << 3);   // pre-swizzled source col (elems)
        const __hip_bfloat16* gsrc = Ehi + (size_t)(n0 + gr) * DIM + k0 + scol;
        __builtin_amdgcn_global_load_lds(
            (const __attribute__((address_space(1))) unsigned int*)gsrc,
            (__attribute__((address_space(3))) unsigned int*)(dst + ((size_t)row << 7)),
            16, 0, 0);
    }
}

// ---- Phase A (R7): 64 rows/block, waves SPLIT ROWS and SHARE the staged code
// chunk (R3/R5/R6 post-mortem: wave-private micro-chunks pinned all variants at
// ~87 us with 4 MFMAs per sync; sharing gives 16 MFMAs/chunk/wave = R1's proven
// density and 4:1 MFMA:stage issue ratio). 3-buffer ring, ONE raw s_barrier per
// chunk + counted vmcnt(8) (never 0 mid-loop), stage issued right after the
// barrier (all waves' prior-chunk ds_reads complete before they reach it).
// setprio(1) around the MFMA cluster. xf[8] = 32 VGPR, truly resident.
// RETROSPECTIVE filter per (row, 64-code tile): u16 trunc-max + u64 margin-mask
// in padded LDS (exclusive slots, no atomics); post-loop global-max expansion.
__global__ __launch_bounds__(256, 4) void dist_cand_kernel(const float* __restrict__ x,
                                                           const __hip_bfloat16* __restrict__ Ehi,
                                                           int* __restrict__ ccnt_g,
                                                           int* __restrict__ clist_g) {
    __shared__ __hip_bfloat16 Bh[3][64 * 128];     // 48 KB ring of 16KB chunks
    __shared__ unsigned short wmax16_s[64][34];    // 4.25 KB (odd dw stride)
    __shared__ unsigned long long mask_s[64][33];  // 16.5 KB (stride 66 dw)
    __shared__ int ccnt_s[64];                     // 256 B

    int tid = threadIdx.x;
    int w = tid >> 6, lane = tid & 63;
    int q = lane >> 4, c = lane & 15;
    int blk = blockIdx.x;                           // 512 blocks, 64 rows each
    int b = blk >> 5;
    int t0 = (blk & 31) << 6;
    const float* xb = x + (size_t)b * DIM * TLEN + t0;

    if (tid < 64) ccnt_s[tid] = 0;

    int trow = (w << 4) + c;                        // row-in-block this lane owns

    // A-frags: xf[kh]: row trow, k = kh*32 + q*8 + j. 32 VGPR, pinned.
    i32x4 xf[8];
#pragma unroll
    for (int kh = 0; kh < 8; ++kh) {
        union { __hip_bfloat16 h[8]; i32x4 v; } u;
#pragma unroll
        for (int j = 0; j < 8; ++j)
            u.h[j] = __float2bfloat16(xb[(size_t)((kh << 5) + (q << 3) + j) * TLEN + trow]);
        xf[kh] = u.v;
        asm volatile("" : "+v"(xf[kh]));
    }

    f32x4 acc[4];
#pragma unroll
    for (int ci = 0; ci < 4; ++ci) acc[ci] = (f32x4){0.f, 0.f, 0.f, 0.f};

    // drain xf loads so in-loop vmcnt counts ONLY stage loads (4/chunk/thread)
    asm volatile("s_waitcnt vmcnt(0)" ::: "memory");
    __syncthreads();                                // LDS inits visible

    stage_chunk(Ehi, &Bh[0][0], 0, w, lane);
    stage_chunk(Ehi, &Bh[1][0], 1, w, lane);

    int cur = 0;                                    // buffer of chunk s
#pragma unroll 1
    for (int nt = 0; nt < 32; ++nt) {
#pragma unroll
        for (int kc2 = 0; kc2 < 2; ++kc2) {
            int s = (nt << 1) + kc2;
            // barrier: all waves done reading chunk s-1 -> its buffer (s+2)%3
            // is safe to restage; raw s_barrier does NOT drain counters.
            asm volatile("s_barrier" ::: "memory");
            int sb = cur == 0 ? 2 : cur - 1;        // (s+2)%3
            if (s + 2 < 64) stage_chunk(Ehi, &Bh[sb][0], s + 2, w, lane);
            if (s < 62)      asm volatile("s_waitcnt vmcnt(8)" ::: "memory");
            else if (s == 62) asm volatile("s_waitcnt vmcnt(4)" ::: "memory");
            else              asm volatile("s_waitcnt vmcnt(0)" ::: "memory");

            const char* basep = reinterpret_cast<const char*>(&Bh[cur][0]);
            __builtin_amdgcn_s_setprio(1);
#pragma unroll
            for (int kh4 = 0; kh4 < 4; ++kh4) {
                bf16x8 af = __builtin_bit_cast(bf16x8, xf[(kc2 << 2) + kh4]);
#pragma unroll
                for (int ci = 0; ci < 4; ++ci) {
                    int rr = (ci << 4) + c;
                    int slot = ((kh4 << 2) | q) ^ (c & 7);
                    bf16x8 cf = *reinterpret_cast<const bf16x8*>(basep + (rr << 8) + (slot << 4));
                    acc[ci] = __builtin_amdgcn_mfma_f32_16x16x32_bf16(cf, af, acc[ci], 0, 0, 0);
                }
            }
            __builtin_amdgcn_s_setprio(0);
            cur = cur == 2 ? 0 : cur + 1;
        }

        // per-nt epilogue: lane holds 16 of the 64 codes (ci*16 + q*4 + reg)
        // for its row trow. Tile max + margin mask -> exclusive LDS slots.
        float a16[16];
#pragma unroll
        for (int ci = 0; ci < 4; ++ci)
#pragma unroll
            for (int reg = 0; reg < 4; ++reg)
                a16[ci * 4 + reg] = acc[ci][reg];
        float m0 = fmaxf(fmaxf(a16[0], a16[1]), fmaxf(a16[2], a16[3]));
        float m1 = fmaxf(fmaxf(a16[4], a16[5]), fmaxf(a16[6], a16[7]));
        float m2 = fmaxf(fmaxf(a16[8], a16[9]), fmaxf(a16[10], a16[11]));
        float m3 = fmaxf(fmaxf(a16[12], a16[13]), fmaxf(a16[14], a16[15]));
        float wmax = fmaxf(fmaxf(m0, m1), fmaxf(m2, m3));
        wmax = fmaxf(wmax, __shfl_xor(wmax, 16, 64));
        wmax = fmaxf(wmax, __shfl_xor(wmax, 32, 64));
        float thrw = wmax - AMARGIN;
        unsigned long long bits = 0;
#pragma unroll
        for (int ci = 0; ci < 4; ++ci)
#pragma unroll
            for (int reg = 0; reg < 4; ++reg)
                if (a16[ci * 4 + reg] >= thrw)
                    bits |= 1ULL << ((ci << 4) + (q << 2) + reg);
        bits |= (unsigned long long)__shfl_xor((long long)bits, 16, 64);
        bits |= (unsigned long long)__shfl_xor((long long)bits, 32, 64);
        if (q == 0) {
            wmax16_s[trow][nt] = (unsigned short)(encf(wmax) >> 16);   // trunc-down
            mask_s[trow][nt] = bits;
        }
#pragma unroll
        for (int ci = 0; ci < 4; ++ci) acc[ci] = (f32x4){0.f, 0.f, 0.f, 0.f};
    }

    __syncthreads();

    // Expansion: retrospective global-max qualification -> compact lists.
    {
        int r = tid >> 2, j4 = tid & 3;             // 4 threads per row
        int m = (blk << 6) + r;
        int g16 = 0;
#pragma unroll
        for (int i = 0; i < 8; ++i) {
            int v = wmax16_s[r][(i << 2) | j4];
            g16 = v > g16 ? v : g16;
        }
        g16 = max(g16, __shfl_xor(g16, 1, 4));
        g16 = max(g16, __shfl_xor(g16, 2, 4));
        float thr = decf((unsigned)g16 << 16) - AMARGIN;
        for (int i = 0; i < 8; ++i) {
            int nt = (i << 2) | j4;
            if (decf((unsigned)wmax16_s[r][nt] << 16) >= thr) {
                unsigned long long bits = mask_s[r][nt];
                while (bits) {
                    int p = __ffsll((long long)bits) - 1; bits &= bits - 1;
                    int pos = atomicAdd(&ccnt_s[r], 1);
                    if (pos < CCAP) clist_g[(size_t)m * CCAP + pos] = (nt << 6) + p;
                }
            }
        }
    }
    __syncthreads();
    if ((tid & 3) == 0) ccnt_g[(blk << 6) + (tid >> 2)] = ccnt_s[tid >> 2];
}

// ---- Phase B: exact recheck over candidate lists (xs computed in-kernel with
// the exact np pairwise chain). Full-scan fallback on overflow keeps exactness
// unconditional.
__global__ __launch_bounds__(256) void recheck_kernel(const float* __restrict__ x,
                                                      const float* __restrict__ cb,
                                                      const float* __restrict__ esq,
                                                      const int* __restrict__ ccnt,
                                                      const int* __restrict__ clist,
                                                      unsigned long long* __restrict__ keys) {
    __shared__ float xT[DIM * 33];

    int tid = threadIdx.x;
    int blk = blockIdx.x;               // 1024 blocks, 32 rows each
    int b = blk >> 6, t0 = (blk & 63) << 5;
    const float* xb = x + (size_t)b * DIM * TLEN + t0;

    {   // coalesced staging: 8 c-rows x 32 t per iter
        int tl = tid & 31, c8 = tid >> 5;
        for (int cc = 0; cc < 32; ++cc) {
            int c = (cc << 3) + c8;
            xT[c * 33 + tl] = xb[(size_t)c * TLEN + tl];
        }
    }
    __syncthreads();

    int g = tid >> 3, l3 = tid & 7;     // group g handles row t0+g
    int m = (b << 11) + t0 + g;

    // xs: np pairwise chain, bit-exact (lane l3 owns accumulator r[l3])
    float h[2];
#pragma unroll
    for (int half = 0; half < 2; ++half) {
        int c0 = half * 128;
        float r = sq_rn(xT[(c0 + l3) * 33 + g]);
        for (int i = 8; i < 128; i += 8)
            r = __fadd_rn(r, sq_rn(xT[(c0 + i + l3) * 33 + g]));
        float a = __fadd_rn(r, __shfl_xor(r, 1, 8));
        float bb = __fadd_rn(a, __shfl_xor(a, 2, 8));
        h[half] = __fadd_rn(bb, __shfl_xor(bb, 4, 8));
    }
    float xs = __fadd_rn(h[0], h[1]);

    int cnt = ccnt[m];
    float bd = 3.4e38f; int bi = 0x7fffffff;

    if (cnt <= CCAP) {
        for (int j = l3; j < cnt; j += 8) {
            int n = clist[(size_t)m * CCAP + j];
            const float* crow = cb + (size_t)n * DIM;
            float d = 0.f;
            for (int k = 0; k < DIM; k += 4) {     // ascending-k fmaf chain == np mm
                float4 cv = *reinterpret_cast<const float4*>(crow + k);
                d = fmaf(xT[(k + 0) * 33 + g], cv.x, d);
                d = fmaf(xT[(k + 1) * 33 + g], cv.y, d);
                d = fmaf(xT[(k + 2) * 33 + g], cv.z, d);
                d = fmaf(xT[(k + 3) * 33 + g], cv.w, d);
            }
            float d2 = __fadd_rn(__fadd_rn(xs, -2.0f * d), esq[n]);
            if (d2 < bd || (d2 == bd && n < bi)) { bd = d2; bi = n; }
        }
    } else {
        for (int n = l3; n < KCODES; n += 8) {
            const float* crow = cb + (size_t)n * DIM;
            float d = 0.f;
            for (int k = 0; k < DIM; k += 4) {
                float4 cv = *reinterpret_cast<const float4*>(crow + k);
                d = fmaf(xT[(k + 0) * 33 + g], cv.x, d);
                d = fmaf(xT[(k + 1) * 33 + g], cv.y, d);
                d = fmaf(xT[(k + 2) * 33 + g], cv.z, d);
                d = fmaf(xT[(k + 3) * 33 + g], cv.w, d);
            }
            float d2 = __fadd_rn(__fadd_rn(xs, -2.0f * d), esq[n]);
            if (d2 < bd || (d2 == bd && n < bi)) { bd = d2; bi = n; }
        }
    }
    for (int off = 1; off < 8; off <<= 1) {
        float od = __shfl_xor(bd, off, 8);
        int   oi = __shfl_xor(bi, off, 8);
        if (od < bd || (od == bd && oi < bi)) { bd = od; bi = oi; }
    }
    if (l3 == 0)
        keys[m] = ((unsigned long long)__float_as_uint(bd) << 32) | (unsigned)(bi & 2047);
}

// ======== fallback path (R5): used only if ws_size is too small ========
__global__ __launch_bounds__(256) void init_keys_kernel(unsigned long long* __restrict__ keys) {
    keys[blockIdx.x * 256 + threadIdx.x] = ~0ULL;
}

__global__ __launch_bounds__(256, 4) void dist_kernel(const float* __restrict__ x,
                                                      const float* __restrict__ cb,
                                                      const float* __restrict__ xsq,
                                                      const float* __restrict__ esq,
                                                      unsigned long long* __restrict__ keys) {
    __shared__ float As[16][128];
    __shared__ float Bs[16][132];
    int blk = blockIdx.x;
    int nt = blk & 15, mt = blk >> 4;
    int m0 = mt << 7;
    int b = m0 >> 11, t0 = m0 & (TLEN - 1);
    int n0 = nt << 7;
    int tid = threadIdx.x;
    int tm = tid >> 4, tn = tid & 15;
    const float* xbase = x + (size_t)b * DIM * TLEN + t0;
    float acc[8][8] = {};
    for (int kk = 0; kk < DIM; kk += 16) {
#pragma unroll
        for (int h = 0; h < 2; ++h) {
            int qq = tid + (h << 8);
            int k = qq >> 5, mq = (qq & 31) << 2;
            float4 v = *reinterpret_cast<const float4*>(xbase + (size_t)(kk + k) * TLEN + mq);
            *reinterpret_cast<float4*>(&As[k][mq]) = v;
        }
#pragma unroll
        for (int h = 0; h < 2; ++h) {
            int qq = tid + (h << 8);
            int nr = qq >> 2, kc = (qq & 3) << 2;
            float4 v = *reinterpret_cast<const float4*>(cb + (size_t)(n0 + nr) * DIM + kk + kc);
            Bs[kc + 0][nr] = v.x; Bs[kc + 1][nr] = v.y;
            Bs[kc + 2][nr] = v.z; Bs[kc + 3][nr] = v.w;
        }
        __syncthreads();
#pragma unroll
        for (int k = 0; k < 16; ++k) {
            float4 a0 = *reinterpret_cast<const float4*>(&As[k][tm << 2]);
            float4 a1 = *reinterpret_cast<const float4*>(&As[k][64 + (tm << 2)]);
            float4 b0 = *reinterpret_cast<const float4*>(&Bs[k][tn << 2]);
            float4 b1 = *reinterpret_cast<const float4*>(&Bs[k][64 + (tn << 2)]);
            float am[8] = {a0.x, a0.y, a0.z, a0.w, a1.x, a1.y, a1.z, a1.w};
            float bn[8] = {b0.x, b0.y, b0.z, b0.w, b1.x, b1.y, b1.z, b1.w};
#pragma unroll
            for (int mi = 0; mi < 8; ++mi)
#pragma unroll
                for (int ni = 0; ni < 8; ++ni)
                    acc[mi][ni] = fmaf(am[mi], bn[ni], acc[mi][ni]);
        }
        __syncthreads();
    }
    int cn[8]; float es[8];
#pragma unroll
    for (int ni = 0; ni < 8; ++ni) {
        cn[ni] = n0 + ((ni < 4) ? (tn << 2) + ni : 60 + (tn << 2) + ni);
        es[ni] = esq[cn[ni]];
    }
#pragma unroll
    for (int mi = 0; mi < 8; ++mi) {
        int m = m0 + ((mi < 4) ? (tm << 2) + mi : 60 + (tm << 2) + mi);
        float xs = xsq[m];
        float bd = 3.4e38f;
        int bi = 0x7fffffff;
#pragma unroll
        for (int ni = 0; ni < 8; ++ni) {
            float d2 = __fadd_rn(__fadd_rn(xs, -2.0f * acc[mi][ni]), es[ni]);
            if (d2 < bd) { bd = d2; bi = cn[ni]; }
        }
        for (int off = 1; off < 16; off <<= 1) {
            float od = __shfl_xor(bd, off, 16);
            int oi = __shfl_xor(bi, off, 16);
            if (od < bd || (od == bd && oi < bi)) { bd = od; bi = oi; }
        }
        if (tn == 0) {
            unsigned long long key =
                ((unsigned long long)__float_as_uint(bd) << 32) | (unsigned)(bi & 2047);
            atomicMin(&keys[m], key);
        }
    }
}
// ======== end fallback ========

// ---- gather + STE output + idx + per-block loss sums (c-oct 32B cb gather)
__global__ __launch_bounds__(256) void gather_kernel(const float* __restrict__ x,
                                                     const float* __restrict__ cb,
                                                     const unsigned long long* __restrict__ keys,
                                                     float* __restrict__ out,
                                                     float* __restrict__ bsum) {
    int tid = threadIdx.x;
    int blk = blockIdx.x;               // 4096 = 16 b x 8 tc x 32 c8
    int c8 = blk & 31, tc = (blk >> 5) & 7, b = blk >> 8;
    int c0 = c8 << 3;
    int t = (tc << 8) + tid;
    int m = (b << 11) + t;
    unsigned idx = (unsigned)(keys[m]) & 2047u;
    const float* crow = cb + (size_t)idx * DIM + c0;
    float4 cv0 = *reinterpret_cast<const float4*>(crow);
    float4 cv1 = *reinterpret_cast<const float4*>(crow + 4);
    if (c8 == 0) out[(size_t)IDX_OFF + m] = (float)idx;

    float qv[8] = {cv0.x, cv0.y, cv0.z, cv0.w, cv1.x, cv1.y, cv1.z, cv1.w};
    __shared__ float wsum[4][8];
    int lane = tid & 63, wid = tid >> 6;
    float sv[8];
#pragma unroll
    for (int cc = 0; cc < 8; ++cc) {
        size_t e = (size_t)b * (DIM * TLEN) + (size_t)(c0 + cc) * TLEN + t;
        float xv = x[e];
        float diff = __fsub_rn(qv[cc], xv);
        out[e] = __fadd_rn(xv, diff);
        float s = __fmul_rn(diff, diff);
        for (int off = 32; off > 0; off >>= 1) s += __shfl_down(s, off, 64);
        sv[cc] = s;
    }
    if (lane == 0) {
#pragma unroll
        for (int cc = 0; cc < 8; ++cc) wsum[wid][cc] = sv[cc];
    }
    __syncthreads();
    if (tid == 0) {
#pragma unroll
        for (int cc = 0; cc < 8; ++cc)
            bsum[(b << 11) + ((c0 + cc) << 3) + tc] =
                ((wsum[0][cc] + wsum[1][cc]) + (wsum[2][cc] + wsum[3][cc]));
    }
}

__global__ __launch_bounds__(1024) void finalize_kernel(const float* __restrict__ bsum,
                                                        float* __restrict__ out) {
    double s = 0.0;
    for (int i = threadIdx.x; i < 32768; i += 1024) s += (double)bsum[i];
    for (int off = 32; off > 0; off >>= 1) s += __shfl_down(s, off, 64);
    __shared__ double wsum[16];
    int lane = threadIdx.x & 63, wid = threadIdx.x >> 6;
    if (lane == 0) wsum[wid] = s;
    __syncthreads();
    if (threadIdx.x == 0) {
        double total = 0.0;
        for (int ww = 0; ww < 16; ++ww) total += wsum[ww];
        float mean = (float)(total / (double)NELEM);
        out[LOSS_OFF] = mean;
        out[LOSS_OFF + 1] = 0.25f * mean;
    }
}

extern "C" void kernel_launch(void* const* d_in, const int* in_sizes, int n_in,
                              void* d_out, int out_size, void* d_ws, size_t ws_size,
                              hipStream_t stream) {
    const float* x  = (const float*)d_in[0];
    const float* cb = (const float*)d_in[1];
    float* out = (float*)d_out;
    char* ws = (char*)d_ws;
    float* xsq = (float*)(ws + OFF_XSQ);
    float* esq = (float*)(ws + OFF_ESQ);
    unsigned long long* keys = (unsigned long long*)(ws + OFF_KEYS);
    float* bsum = (float*)(ws + OFF_BSUM);

    if (ws_size >= WS_NEED) {
        __hip_bfloat16* Ehi = (__hip_bfloat16*)(ws + OFF_EHI);
        int* ccnt  = (int*)(ws + OFF_CCNT);
        int* clist = (int*)(ws + OFF_CLIST);
        prep_e_kernel<<<KCODES / 4, 256, 0, stream>>>(cb, Ehi, esq);
        dist_cand_kernel<<<NROWS / 64, 256, 0, stream>>>(x, Ehi, ccnt, clist);
        recheck_kernel<<<NROWS / 32, 256, 0, stream>>>(x, cb, esq, ccnt, clist, keys);
    } else {
        esq_kernel<<<KCODES / 256, 256, 0, stream>>>(cb, esq);
        xsq_kernel<<<NROWS / 256, 256, 0, stream>>>(x, xsq);
        init_keys_kernel<<<NROWS / 256, 256, 0, stream>>>(keys);
        dist_kernel<<<(NROWS / 128) * (KCODES / 128), 256, 0, stream>>>(x, cb, xsq, esq, keys);
    }
    gather_kernel<<<(NB * 8 * 32), 256, 0, stream>>>(x, cb, keys, out, bsum);
    finalize_kernel<<<1, 1024, 0, stream>>>(bsum, out);
}

// Round 8
// 195.417 us; speedup vs baseline: 1.0957x; 1.0957x over previous
//
#include <hip/hip_runtime.h>
#include <hip/hip_bf16.h>

// Problem constants
#define KCODES 2048
#define DIM 256
#define TLEN 2048
#define NB 16
#define NROWS (NB * TLEN)          // 32768 rows (b*t)
#define NELEM (NB * DIM * TLEN)    // 8388608 elements of x / quant
#define LOSS_OFF NELEM
#define IDX_OFF (NELEM + 2)

// Margin in the a = (bf16 dot) domain (R5/R6/R7-proven, absmax 0.0 each time).
// s = xsq - 2a + esq; filter on a alone with margin covering 2*bf16-err
// (a-domain 1.5e-3) + esq spread/2 (~3e-5). u32 amax storage (no truncation)
// is strictly more conservative than the proven u16 variant.
#define AMARGIN 1.8e-3f

// Candidate list capacity per row (retrospective global-max qualification,
// E[#cands] ~ 3-10, proven small in R5-R7). Overflow -> exact full scan.
#define CCAP 48

// ws layout (bytes) — total ~29.5 MB
#define OFF_XSQ   0ull                       // 131072 (fallback path only)
#define OFF_ESQ   131072ull                  // 8192
#define OFF_KEYS  139264ull                  // 262144
#define OFF_BSUM  401408ull                  // 131072
#define OFF_EHI   532480ull                  // 1048576
#define OFF_XHI   1581056ull                 // 16777216
#define OFF_AMAX  18358272ull                // 32*32768*4  = 4194304
#define OFF_MASK  22552576ull                // 32*32768*8  = 8388608
#define WS_NEED   30941184ull

typedef __bf16 bf16x8 __attribute__((ext_vector_type(8)));
typedef float  f32x4  __attribute__((ext_vector_type(4)));

__device__ __forceinline__ float sq_rn(float v) { return __fmul_rn(v, v); }

// order-preserving float<->u32 encoding (uint order == float order)
__device__ __forceinline__ unsigned encf(float f) {
    unsigned u = __float_as_uint(f);
    return (u & 0x80000000u) ? ~u : (u | 0x80000000u);
}
__device__ __forceinline__ float decf(unsigned k) {
    return __uint_as_float((k & 0x80000000u) ? (k & 0x7FFFFFFFu) : ~k);
}

// ---- x_sq: numpy pairwise sum (fallback path only)
__global__ __launch_bounds__(256) void xsq_kernel(const float* __restrict__ x,
                                                  float* __restrict__ xsq) {
    int m = blockIdx.x * 256 + threadIdx.x;
    int b = m >> 11, t = m & (TLEN - 1);
    const float* p = x + (size_t)b * DIM * TLEN + t;
    float h[2];
#pragma unroll
    for (int half = 0; half < 2; ++half) {
        int c0 = half * 128;
        float r[8];
#pragma unroll
        for (int j = 0; j < 8; ++j) r[j] = sq_rn(p[(size_t)(c0 + j) * TLEN]);
        for (int i = 8; i < 128; i += 8) {
#pragma unroll
            for (int j = 0; j < 8; ++j)
                r[j] = __fadd_rn(r[j], sq_rn(p[(size_t)(c0 + i + j) * TLEN]));
        }
        h[half] = __fadd_rn(__fadd_rn(__fadd_rn(r[0], r[1]), __fadd_rn(r[2], r[3])),
                            __fadd_rn(__fadd_rn(r[4], r[5]), __fadd_rn(r[6], r[7])));
    }
    xsq[m] = __fadd_rn(h[0], h[1]);
}

// ---- esq standalone (fallback path only)
__global__ __launch_bounds__(256) void esq_kernel(const float* __restrict__ cb,
                                                  float* __restrict__ esq) {
    int k = blockIdx.x * 256 + threadIdx.x;
    const float* p = cb + (size_t)k * DIM;
    float h[2];
#pragma unroll
    for (int half = 0; half < 2; ++half) {
        int c0 = half * 128;
        float r[8];
#pragma unroll
        for (int j = 0; j < 8; ++j) r[j] = sq_rn(p[c0 + j]);
        for (int i = 8; i < 128; i += 8) {
#pragma unroll
            for (int j = 0; j < 8; ++j)
                r[j] = __fadd_rn(r[j], sq_rn(p[c0 + i + j]));
        }
        h[half] = __fadd_rn(__fadd_rn(__fadd_rn(r[0], r[1]), __fadd_rn(r[2], r[3])),
                            __fadd_rn(__fadd_rn(r[4], r[5]), __fadd_rn(r[6], r[7])));
    }
    esq[k] = __fadd_rn(h[0], h[1]);
}

// ---- x (layout [c][t] fp32) -> Xhi [m][k] bf16 (transpose + round; R0-proven)
__global__ __launch_bounds__(256) void split_x_kernel(const float* __restrict__ x,
                                                      __hip_bfloat16* __restrict__ Xhi) {
    __shared__ float tb[32][72];
    int blk = blockIdx.x;
    int tt = blk & 31, cc = (blk >> 5) & 7, b = blk >> 8;
    int c0 = cc << 5, t0 = tt << 6;
    int tid = threadIdx.x;
    {
        int c_l = tid >> 3, t8 = (tid & 7) << 3;
        const float* src = x + (size_t)b * DIM * TLEN + (size_t)(c0 + c_l) * TLEN + t0 + t8;
        float4 v0 = *reinterpret_cast<const float4*>(src);
        float4 v1 = *reinterpret_cast<const float4*>(src + 4);
        tb[c_l][t8 + 0] = v0.x; tb[c_l][t8 + 1] = v0.y; tb[c_l][t8 + 2] = v0.z; tb[c_l][t8 + 3] = v0.w;
        tb[c_l][t8 + 4] = v1.x; tb[c_l][t8 + 5] = v1.y; tb[c_l][t8 + 6] = v1.z; tb[c_l][t8 + 7] = v1.w;
    }
    __syncthreads();
    {
        int cp = tid & 3, m_l = tid >> 2;
        size_t m = (size_t)b * TLEN + t0 + m_l;
        alignas(16) __hip_bfloat16 h8[8];
#pragma unroll
        for (int j = 0; j < 8; ++j)
            h8[j] = __float2bfloat16(tb[(cp << 3) + j][m_l]);
        *reinterpret_cast<int4*>(Xhi + m * DIM + c0 + (cp << 3)) = *reinterpret_cast<int4*>(h8);
    }
}

// ---- fused prep: cb -> Ehi (bf16) + esq (exact np pairwise chain, bit-identical)
__global__ __launch_bounds__(256) void prep_e_kernel(const float* __restrict__ cb,
                                                     __hip_bfloat16* __restrict__ Ehi,
                                                     float* __restrict__ esq) {
    int tid = threadIdx.x;
    int w = tid >> 6, lane = tid & 63;
    int k = (blockIdx.x << 2) + w;          // code row
    const float* p = cb + (size_t)k * DIM;

    float4 v = *reinterpret_cast<const float4*>(p + (lane << 2));
    alignas(8) __hip_bfloat16 h4[4];
    h4[0] = __float2bfloat16(v.x); h4[1] = __float2bfloat16(v.y);
    h4[2] = __float2bfloat16(v.z); h4[3] = __float2bfloat16(v.w);
    *reinterpret_cast<int2*>(Ehi + (size_t)k * DIM + (lane << 2)) = *reinterpret_cast<int2*>(h4);

    if (lane < 16) {
        int c0 = (lane >> 3) << 7, j = lane & 7;
        float r = sq_rn(p[c0 + j]);
        for (int i = 8; i < 128; i += 8)
            r = __fadd_rn(r, sq_rn(p[c0 + i + j]));
        float a  = __fadd_rn(r,  __shfl_xor(r, 1, 16));
        float b2 = __fadd_rn(a,  __shfl_xor(a, 2, 16));
        float h  = __fadd_rn(b2, __shfl_xor(b2, 4, 16));
        float tot = __fadd_rn(h, __shfl_xor(h, 8, 16));   // h0 + h1, own-first
        if (lane == 0) esq[k] = tot;
    }
}

// ---- Phase A: the R1-PROVEN 61us loop (128x128 tile, BK=64, global_load_lds
// with pre-swizzled source, 2 barriers/k-step, 32 MFMA/wave between barriers,
// conflict-free reads). ONLY the output path is changed: a-domain retrospective
// filter data — per (row, 64-code tile tb) store encf(amax) u32 + u64 margin
// mask, TB-MAJOR [tb][m] so the 16 q==0 lanes write 16 consecutive words
// (coalesced; kills R1's 74MB RMW write amplification).
__global__ __launch_bounds__(256, 4) void mfma_dist_kernel(const __hip_bfloat16* __restrict__ Xhi,
                                                           const __hip_bfloat16* __restrict__ Ehi,
                                                           unsigned* __restrict__ amax_g,
                                                           unsigned long long* __restrict__ mask_g) {
    __shared__ __hip_bfloat16 Ah[128 * 64];   // 16KB, x rows, swizzled layout
    __shared__ __hip_bfloat16 Bh[128 * 64];   // 16KB, codebook rows, swizzled

    int blk = blockIdx.x;
    int nt = blk & 15, mt = blk >> 4;
    int m0 = mt << 7, n0 = nt << 7;
    int tid = threadIdx.x;
    int w = tid >> 6, lane = tid & 63;
    int q = lane >> 4, c = lane & 15;
    int mhalf = w >> 1, nhalf = w & 1;

    int srow = lane >> 3;                      // 0..7 within chunk
    int scol = ((lane & 7) ^ srow) << 3;       // pre-swizzled source col (elems)
    const __hip_bfloat16* gA = Xhi + (size_t)(m0 + (w << 5) + srow) * DIM + scol;
    const __hip_bfloat16* gB = Ehi + (size_t)(n0 + (w << 5) + srow) * DIM + scol;

    f32x4 acc[4][4];   // [ci (code subtile)][mi (x-row subtile)]
#pragma unroll
    for (int ci = 0; ci < 4; ++ci)
#pragma unroll
        for (int mi = 0; mi < 4; ++mi) acc[ci][mi] = (f32x4){0.f, 0.f, 0.f, 0.f};

    const char* AhB = reinterpret_cast<const char*>(Ah);
    const char* BhB = reinterpret_cast<const char*>(Bh);
    int swzc = (c & 7) << 4;                   // read-side XOR

    for (int kk = 0; kk < DIM; kk += 64) {
#pragma unroll
        for (int j = 0; j < 4; ++j)
            __builtin_amdgcn_global_load_lds(
                (const __attribute__((address_space(1))) unsigned int*)(gA + (size_t)(j << 3) * DIM + kk),
                (__attribute__((address_space(3))) unsigned int*)(&Ah[((w << 2) + j) << 9]),
                16, 0, 0);
#pragma unroll
        for (int j = 0; j < 4; ++j)
            __builtin_amdgcn_global_load_lds(
                (const __attribute__((address_space(1))) unsigned int*)(gB + (size_t)(j << 3) * DIM + kk),
                (__attribute__((address_space(3))) unsigned int*)(&Bh[((w << 2) + j) << 9]),
                16, 0, 0);
        __syncthreads();
#pragma unroll
        for (int kh = 0; kh < 2; ++kh) {
            int swz = ((kh << 6) | (q << 4)) ^ swzc;
            bf16x8 xf[4], cf[4];
#pragma unroll
            for (int mi = 0; mi < 4; ++mi) {
                int row = (mhalf << 6) + (mi << 4) + c;
                xf[mi] = *reinterpret_cast<const bf16x8*>(AhB + (row << 7) + swz);
            }
#pragma unroll
            for (int ci = 0; ci < 4; ++ci) {
                int row = (nhalf << 6) + (ci << 4) + c;
                cf[ci] = *reinterpret_cast<const bf16x8*>(BhB + (row << 7) + swz);
            }
#pragma unroll
            for (int ci = 0; ci < 4; ++ci)
#pragma unroll
                for (int mi = 0; mi < 4; ++mi)
                    acc[ci][mi] = __builtin_amdgcn_mfma_f32_16x16x32_bf16(cf[ci], xf[mi], acc[ci][mi], 0, 0, 0);
        }
        __syncthreads();
    }

    // Epilogue: lane (q,c) holds codes {ci*16+q*4+reg} of the 64-code tile
    // tb = nt*2+nhalf for x-row m0 + mhalf*64 + mi*16 + c. amax tree + 2 shfls,
    // margin mask u64 + 2 shfls, coalesced tb-major stores (q==0 lanes only).
    int tb = (nt << 1) | nhalf;
#pragma unroll
    for (int mi = 0; mi < 4; ++mi) {
        float a16[16];
#pragma unroll
        for (int ci = 0; ci < 4; ++ci)
#pragma unroll
            for (int reg = 0; reg < 4; ++reg)
                a16[ci * 4 + reg] = acc[ci][mi][reg];
        float m01 = fmaxf(fmaxf(a16[0], a16[1]), fmaxf(a16[2], a16[3]));
        float m23 = fmaxf(fmaxf(a16[4], a16[5]), fmaxf(a16[6], a16[7]));
        float m45 = fmaxf(fmaxf(a16[8], a16[9]), fmaxf(a16[10], a16[11]));
        float m67 = fmaxf(fmaxf(a16[12], a16[13]), fmaxf(a16[14], a16[15]));
        float amax = fmaxf(fmaxf(m01, m23), fmaxf(m45, m67));
        amax = fmaxf(amax, __shfl_xor(amax, 16, 64));
        amax = fmaxf(amax, __shfl_xor(amax, 32, 64));
        float thrw = amax - AMARGIN;
        unsigned long long bits = 0;
#pragma unroll
        for (int v = 0; v < 16; ++v)
            if (a16[v] >= thrw)
                bits |= 1ULL << (((v >> 2) << 4) + (q << 2) + (v & 3));
        bits |= (unsigned long long)__shfl_xor((long long)bits, 16, 64);
        bits |= (unsigned long long)__shfl_xor((long long)bits, 32, 64);
        if (q == 0) {
            int m = m0 + (mhalf << 6) + (mi << 4) + c;
            amax_g[(size_t)tb * NROWS + m] = encf(amax);
            mask_g[(size_t)tb * NROWS + m] = bits;
        }
    }
}

// ---- Phase B: retrospective global-max qualification + exact recheck.
// Per row: 32 (amax,mask) pairs -> gmax -> expand qualifying tiles' masks into
// the proven LDS clist (atomicAdd, 8-lane group = one wave, order-independent
// final min) -> exact fp32 dots. xs computed in-kernel (proven np chain).
// Full-scan fallback on overflow keeps exactness unconditional.
__global__ __launch_bounds__(256) void recheck_kernel(const float* __restrict__ x,
                                                      const float* __restrict__ cb,
                                                      const float* __restrict__ esq,
                                                      const unsigned* __restrict__ amax_g,
                                                      const unsigned long long* __restrict__ mask_g,
                                                      unsigned long long* __restrict__ keys) {
    __shared__ float xT[DIM * 33];
    __shared__ int clist[32][CCAP];
    __shared__ int ccnt[32];

    int tid = threadIdx.x;
    int blk = blockIdx.x;               // 1024 blocks, 32 rows each
    int b = blk >> 6, t0 = (blk & 63) << 5;
    const float* xb = x + (size_t)b * DIM * TLEN + t0;

    if (tid < 32) ccnt[tid] = 0;
    {   // coalesced staging: 8 c-rows x 32 t per iter
        int tl = tid & 31, c8 = tid >> 5;
        for (int cc = 0; cc < 32; ++cc) {
            int c = (cc << 3) + c8;
            xT[c * 33 + tl] = xb[(size_t)c * TLEN + tl];
        }
    }
    __syncthreads();

    int g = tid >> 3, l3 = tid & 7;     // group g handles row t0+g
    int m = (b << 11) + t0 + g;

    // xs: np pairwise chain, bit-exact (lane l3 owns accumulator r[l3])
    float h[2];
#pragma unroll
    for (int half = 0; half < 2; ++half) {
        int c0 = half * 128;
        float r = sq_rn(xT[(c0 + l3) * 33 + g]);
        for (int i = 8; i < 128; i += 8)
            r = __fadd_rn(r, sq_rn(xT[(c0 + i + l3) * 33 + g]));
        float a = __fadd_rn(r, __shfl_xor(r, 1, 8));
        float bb = __fadd_rn(a, __shfl_xor(a, 2, 8));
        h[half] = __fadd_rn(bb, __shfl_xor(bb, 4, 8));
    }
    float xs = __fadd_rn(h[0], h[1]);

    // global max over 32 tiles (encoded u32 preserves float order)
    unsigned am4[4];
    unsigned ge = 0;
#pragma unroll
    for (int j = 0; j < 4; ++j) {
        am4[j] = amax_g[(size_t)(l3 * 4 + j) * NROWS + m];
        ge = max(ge, am4[j]);
    }
    for (int off = 1; off < 8; off <<= 1)
        ge = max(ge, (unsigned)__shfl_xor((int)ge, off, 8));
    float thr = decf(ge) - AMARGIN;

    // expand qualifying tiles
#pragma unroll
    for (int j = 0; j < 4; ++j) {
        if (decf(am4[j]) >= thr) {
            unsigned long long bits = mask_g[(size_t)(l3 * 4 + j) * NROWS + m];
            while (bits) {
                int p = __ffsll((long long)bits) - 1; bits &= bits - 1;
                int pos = atomicAdd(&ccnt[g], 1);
                if (pos < CCAP) clist[g][pos] = (l3 * 4 + j) * 64 + p;
            }
        }
    }
    __syncthreads();

    int cnt = ccnt[g];
    float bd = 3.4e38f; int bi = 0x7fffffff;

    if (cnt <= CCAP) {
        for (int j = l3; j < cnt; j += 8) {
            int n = clist[g][j];
            const float* crow = cb + (size_t)n * DIM;
            float d = 0.f;
            for (int k = 0; k < DIM; k += 4) {     // ascending-k fmaf chain == np mm
                float4 cv = *reinterpret_cast<const float4*>(crow + k);
                d = fmaf(xT[(k + 0) * 33 + g], cv.x, d);
                d = fmaf(xT[(k + 1) * 33 + g], cv.y, d);
                d = fmaf(xT[(k + 2) * 33 + g], cv.z, d);
                d = fmaf(xT[(k + 3) * 33 + g], cv.w, d);
            }
            float d2 = __fadd_rn(__fadd_rn(xs, -2.0f * d), esq[n]);
            if (d2 < bd || (d2 == bd && n < bi)) { bd = d2; bi = n; }
        }
    } else {
        // overflow fallback: exact full scan (same formula, any order is fine)
        for (int n = l3; n < KCODES; n += 8) {
            const float* crow = cb + (size_t)n * DIM;
            float d = 0.f;
            for (int k = 0; k < DIM; k += 4) {
                float4 cv = *reinterpret_cast<const float4*>(crow + k);
                d = fmaf(xT[(k + 0) * 33 + g], cv.x, d);
                d = fmaf(xT[(k + 1) * 33 + g], cv.y, d);
                d = fmaf(xT[(k + 2) * 33 + g], cv.z, d);
                d = fmaf(xT[(k + 3) * 33 + g], cv.w, d);
            }
            float d2 = __fadd_rn(__fadd_rn(xs, -2.0f * d), esq[n]);
            if (d2 < bd || (d2 == bd && n < bi)) { bd = d2; bi = n; }
        }
    }
    for (int off = 1; off < 8; off <<= 1) {
        float od = __shfl_xor(bd, off, 8);
        int   oi = __shfl_xor(bi, off, 8);
        if (od < bd || (od == bd && oi < bi)) { bd = od; bi = oi; }
    }
    if (l3 == 0)
        keys[m] = ((unsigned long long)__float_as_uint(bd) << 32) | (unsigned)(bi & 2047);
}

// ======== fallback path (R5): used only if ws_size is too small ========
__global__ __launch_bounds__(256) void init_keys_kernel(unsigned long long* __restrict__ keys) {
    keys[blockIdx.x * 256 + threadIdx.x] = ~0ULL;
}

__global__ __launch_bounds__(256, 4) void dist_kernel(const float* __restrict__ x,
                                                      const float* __restrict__ cb,
                                                      const float* __restrict__ xsq,
                                                      const float* __restrict__ esq,
                                                      unsigned long long* __restrict__ keys) {
    __shared__ float As[16][128];
    __shared__ float Bs[16][132];
    int blk = blockIdx.x;
    int nt = blk & 15, mt = blk >> 4;
    int m0 = mt << 7;
    int b = m0 >> 11, t0 = m0 & (TLEN - 1);
    int n0 = nt << 7;
    int tid = threadIdx.x;
    int tm = tid >> 4, tn = tid & 15;
    const float* xbase = x + (size_t)b * DIM * TLEN + t0;
    float acc[8][8] = {};
    for (int kk = 0; kk < DIM; kk += 16) {
#pragma unroll
        for (int h = 0; h < 2; ++h) {
            int qq = tid + (h << 8);
            int k = qq >> 5, mq = (qq & 31) << 2;
            float4 v = *reinterpret_cast<const float4*>(xbase + (size_t)(kk + k) * TLEN + mq);
            *reinterpret_cast<float4*>(&As[k][mq]) = v;
        }
#pragma unroll
        for (int h = 0; h < 2; ++h) {
            int qq = tid + (h << 8);
            int nr = qq >> 2, kc = (qq & 3) << 2;
            float4 v = *reinterpret_cast<const float4*>(cb + (size_t)(n0 + nr) * DIM + kk + kc);
            Bs[kc + 0][nr] = v.x; Bs[kc + 1][nr] = v.y;
            Bs[kc + 2][nr] = v.z; Bs[kc + 3][nr] = v.w;
        }
        __syncthreads();
#pragma unroll
        for (int k = 0; k < 16; ++k) {
            float4 a0 = *reinterpret_cast<const float4*>(&As[k][tm << 2]);
            float4 a1 = *reinterpret_cast<const float4*>(&As[k][64 + (tm << 2)]);
            float4 b0 = *reinterpret_cast<const float4*>(&Bs[k][tn << 2]);
            float4 b1 = *reinterpret_cast<const float4*>(&Bs[k][64 + (tn << 2)]);
            float am[8] = {a0.x, a0.y, a0.z, a0.w, a1.x, a1.y, a1.z, a1.w};
            float bn[8] = {b0.x, b0.y, b0.z, b0.w, b1.x, b1.y, b1.z, b1.w};
#pragma unroll
            for (int mi = 0; mi < 8; ++mi)
#pragma unroll
                for (int ni = 0; ni < 8; ++ni)
                    acc[mi][ni] = fmaf(am[mi], bn[ni], acc[mi][ni]);
        }
        __syncthreads();
    }
    int cn[8]; float es[8];
#pragma unroll
    for (int ni = 0; ni < 8; ++ni) {
        cn[ni] = n0 + ((ni < 4) ? (tn << 2) + ni : 60 + (tn << 2) + ni);
        es[ni] = esq[cn[ni]];
    }
#pragma unroll
    for (int mi = 0; mi < 8; ++mi) {
        int m = m0 + ((mi < 4) ? (tm << 2) + mi : 60 + (tm << 2) + mi);
        float xs = xsq[m];
        float bd = 3.4e38f;
        int bi = 0x7fffffff;
#pragma unroll
        for (int ni = 0; ni < 8; ++ni) {
            float d2 = __fadd_rn(__fadd_rn(xs, -2.0f * acc[mi][ni]), es[ni]);
            if (d2 < bd) { bd = d2; bi = cn[ni]; }
        }
        for (int off = 1; off < 16; off <<= 1) {
            float od = __shfl_xor(bd, off, 16);
            int oi = __shfl_xor(bi, off, 16);
            if (od < bd || (od == bd && oi < bi)) { bd = od; bi = oi; }
        }
        if (tn == 0) {
            unsigned long long key =
                ((unsigned long long)__float_as_uint(bd) << 32) | (unsigned)(bi & 2047);
            atomicMin(&keys[m], key);
        }
    }
}
// ======== end fallback ========

// ---- gather + STE output + idx + per-block loss sums (c-oct 32B cb gather)
__global__ __launch_bounds__(256) void gather_kernel(const float* __restrict__ x,
                                                     const float* __restrict__ cb,
                                                     const unsigned long long* __restrict__ keys,
                                                     float* __restrict__ out,
                                                     float* __restrict__ bsum) {
    int tid = threadIdx.x;
    int blk = blockIdx.x;               // 4096 = 16 b x 8 tc x 32 c8
    int c8 = blk & 31, tc = (blk >> 5) & 7, b = blk >> 8;
    int c0 = c8 << 3;
    int t = (tc << 8) + tid;
    int m = (b << 11) + t;
    unsigned idx = (unsigned)(keys[m]) & 2047u;
    const float* crow = cb + (size_t)idx * DIM + c0;
    float4 cv0 = *reinterpret_cast<const float4*>(crow);
    float4 cv1 = *reinterpret_cast<const float4*>(crow + 4);
    if (c8 == 0) out[(size_t)IDX_OFF + m] = (float)idx;

    float qv[8] = {cv0.x, cv0.y, cv0.z, cv0.w, cv1.x, cv1.y, cv1.z, cv1.w};
    __shared__ float wsum[4][8];
    int lane = tid & 63, wid = tid >> 6;
    float sv[8];
#pragma unroll
    for (int cc = 0; cc < 8; ++cc) {
        size_t e = (size_t)b * (DIM * TLEN) + (size_t)(c0 + cc) * TLEN + t;
        float xv = x[e];
        float diff = __fsub_rn(qv[cc], xv);
        out[e] = __fadd_rn(xv, diff);
        float s = __fmul_rn(diff, diff);
        for (int off = 32; off > 0; off >>= 1) s += __shfl_down(s, off, 64);
        sv[cc] = s;
    }
    if (lane == 0) {
#pragma unroll
        for (int cc = 0; cc < 8; ++cc) wsum[wid][cc] = sv[cc];
    }
    __syncthreads();
    if (tid == 0) {
#pragma unroll
        for (int cc = 0; cc < 8; ++cc)
            bsum[(b << 11) + ((c0 + cc) << 3) + tc] =
                ((wsum[0][cc] + wsum[1][cc]) + (wsum[2][cc] + wsum[3][cc]));
    }
}

__global__ __launch_bounds__(1024) void finalize_kernel(const float* __restrict__ bsum,
                                                        float* __restrict__ out) {
    double s = 0.0;
    for (int i = threadIdx.x; i < 32768; i += 1024) s += (double)bsum[i];
    for (int off = 32; off > 0; off >>= 1) s += __shfl_down(s, off, 64);
    __shared__ double wsum[16];
    int lane = threadIdx.x & 63, wid = threadIdx.x >> 6;
    if (lane == 0) wsum[wid] = s;
    __syncthreads();
    if (threadIdx.x == 0) {
        double total = 0.0;
        for (int ww = 0; ww < 16; ++ww) total += wsum[ww];
        float mean = (float)(total / (double)NELEM);
        out[LOSS_OFF] = mean;
        out[LOSS_OFF + 1] = 0.25f * mean;
    }
}

extern "C" void kernel_launch(void* const* d_in, const int* in_sizes, int n_in,
                              void* d_out, int out_size, void* d_ws, size_t ws_size,
                              hipStream_t stream) {
    const float* x  = (const float*)d_in[0];
    const float* cb = (const float*)d_in[1];
    float* out = (float*)d_out;
    char* ws = (char*)d_ws;
    float* xsq = (float*)(ws + OFF_XSQ);
    float* esq = (float*)(ws + OFF_ESQ);
    unsigned long long* keys = (unsigned long long*)(ws + OFF_KEYS);
    float* bsum = (float*)(ws + OFF_BSUM);

    if (ws_size >= WS_NEED) {
        __hip_bfloat16* Ehi = (__hip_bfloat16*)(ws + OFF_EHI);
        __hip_bfloat16* Xhi = (__hip_bfloat16*)(ws + OFF_XHI);
        unsigned* amax_g = (unsigned*)(ws + OFF_AMAX);
        unsigned long long* mask_g = (unsigned long long*)(ws + OFF_MASK);
        prep_e_kernel<<<KCODES / 4, 256, 0, stream>>>(cb, Ehi, esq);
        split_x_kernel<<<NB * 8 * 32, 256, 0, stream>>>(x, Xhi);
        mfma_dist_kernel<<<(NROWS / 128) * (KCODES / 128), 256, 0, stream>>>(
            Xhi, Ehi, amax_g, mask_g);
        recheck_kernel<<<NROWS / 32, 256, 0, stream>>>(x, cb, esq, amax_g, mask_g, keys);
    } else {
        esq_kernel<<<KCODES / 256, 256, 0, stream>>>(cb, esq);
        xsq_kernel<<<NROWS / 256, 256, 0, stream>>>(x, xsq);
        init_keys_kernel<<<NROWS / 256, 256, 0, stream>>>(keys);
        dist_kernel<<<(NROWS / 128) * (KCODES / 128), 256, 0, stream>>>(x, cb, xsq, esq, keys);
    }
    gather_kernel<<<(NB * 8 * 32), 256, 0, stream>>>(x, cb, keys, out, bsum);
    finalize_kernel<<<1, 1024, 0, stream>>>(bsum, out);
}

// Round 11
// 185.225 us; speedup vs baseline: 1.1560x; 1.0550x over previous
//
#include <hip/hip_runtime.h>
#include <hip/hip_bf16.h>

// Problem constants
#define KCODES 2048
#define DIM 256
#define TLEN 2048
#define NB 16
#define NROWS (NB * TLEN)          // 32768 rows (b*t)
#define NELEM (NB * DIM * TLEN)    // 8388608 elements of x / quant
#define LOSS_OFF NELEM
#define IDX_OFF (NELEM + 2)

// Margin in the a = (bf16 dot) domain (R5-R8 proven, absmax 0.0 each time).
#define AMARGIN 1.8e-3f

// Candidate list capacity per row (retrospective global-max qualification,
// E[#cands] ~ 3-10). Overflow -> exact full scan.
#define CCAP 48

// ws layout (bytes) — total ~29.5 MB
#define OFF_XSQ   0ull                       // 131072 (fallback path only)
#define OFF_ESQ   131072ull                  // 8192
#define OFF_KEYS  139264ull                  // keys (fallback path only)
#define OFF_BSUM  401408ull                  // 1024 * 64B padded doubles (main)
#define OFF_EHI   532480ull                  // 1048576
#define OFF_XHI   1581056ull                 // 16777216
#define OFF_AMAX  18358272ull                // 32*32768*4  = 4194304
#define OFF_MASK  22552576ull                // 32*32768*8  = 8388608
#define WS_NEED   30941184ull

typedef __bf16 bf16x8 __attribute__((ext_vector_type(8)));
typedef float  f32x4  __attribute__((ext_vector_type(4)));

__device__ __forceinline__ float sq_rn(float v) { return __fmul_rn(v, v); }

// order-preserving float<->u32 encoding (uint order == float order)
__device__ __forceinline__ unsigned encf(float f) {
    unsigned u = __float_as_uint(f);
    return (u & 0x80000000u) ? ~u : (u | 0x80000000u);
}
__device__ __forceinline__ float decf(unsigned k) {
    return __uint_as_float((k & 0x80000000u) ? (k & 0x7FFFFFFFu) : ~k);
}

// ---- x_sq: numpy pairwise sum (fallback path only)
__global__ __launch_bounds__(256) void xsq_kernel(const float* __restrict__ x,
                                                  float* __restrict__ xsq) {
    int m = blockIdx.x * 256 + threadIdx.x;
    int b = m >> 11, t = m & (TLEN - 1);
    const float* p = x + (size_t)b * DIM * TLEN + t;
    float h[2];
#pragma unroll
    for (int half = 0; half < 2; ++half) {
        int c0 = half * 128;
        float r[8];
#pragma unroll
        for (int j = 0; j < 8; ++j) r[j] = sq_rn(p[(size_t)(c0 + j) * TLEN]);
        for (int i = 8; i < 128; i += 8) {
#pragma unroll
            for (int j = 0; j < 8; ++j)
                r[j] = __fadd_rn(r[j], sq_rn(p[(size_t)(c0 + i + j) * TLEN]));
        }
        h[half] = __fadd_rn(__fadd_rn(__fadd_rn(r[0], r[1]), __fadd_rn(r[2], r[3])),
                            __fadd_rn(__fadd_rn(r[4], r[5]), __fadd_rn(r[6], r[7])));
    }
    xsq[m] = __fadd_rn(h[0], h[1]);
}

// ---- esq standalone (fallback path only)
__global__ __launch_bounds__(256) void esq_kernel(const float* __restrict__ cb,
                                                  float* __restrict__ esq) {
    int k = blockIdx.x * 256 + threadIdx.x;
    const float* p = cb + (size_t)k * DIM;
    float h[2];
#pragma unroll
    for (int half = 0; half < 2; ++half) {
        int c0 = half * 128;
        float r[8];
#pragma unroll
        for (int j = 0; j < 8; ++j) r[j] = sq_rn(p[c0 + j]);
        for (int i = 8; i < 128; i += 8) {
#pragma unroll
            for (int j = 0; j < 8; ++j)
                r[j] = __fadd_rn(r[j], sq_rn(p[c0 + i + j]));
        }
        h[half] = __fadd_rn(__fadd_rn(__fadd_rn(r[0], r[1]), __fadd_rn(r[2], r[3])),
                            __fadd_rn(__fadd_rn(r[4], r[5]), __fadd_rn(r[6], r[7])));
    }
    esq[k] = __fadd_rn(h[0], h[1]);
}

// ---- fused prep: blocks [0,512) do cb -> Ehi + esq (exact np chain, proven);
// blocks [512, 4608) do x -> Xhi transpose+round (R0-proven).
__global__ __launch_bounds__(256) void prep_kernel(const float* __restrict__ cb,
                                                   const float* __restrict__ x,
                                                   __hip_bfloat16* __restrict__ Ehi,
                                                   float* __restrict__ esq,
                                                   __hip_bfloat16* __restrict__ Xhi) {
    int tid = threadIdx.x;
    if (blockIdx.x < 512) {
        int w = tid >> 6, lane = tid & 63;
        int k = ((int)blockIdx.x << 2) + w;          // code row
        const float* p = cb + (size_t)k * DIM;

        float4 v = *reinterpret_cast<const float4*>(p + (lane << 2));
        alignas(8) __hip_bfloat16 h4[4];
        h4[0] = __float2bfloat16(v.x); h4[1] = __float2bfloat16(v.y);
        h4[2] = __float2bfloat16(v.z); h4[3] = __float2bfloat16(v.w);
        *reinterpret_cast<int2*>(Ehi + (size_t)k * DIM + (lane << 2)) = *reinterpret_cast<int2*>(h4);

        if (lane < 16) {
            int c0 = (lane >> 3) << 7, j = lane & 7;
            float r = sq_rn(p[c0 + j]);
            for (int i = 8; i < 128; i += 8)
                r = __fadd_rn(r, sq_rn(p[c0 + i + j]));
            float a  = __fadd_rn(r,  __shfl_xor(r, 1, 16));
            float b2 = __fadd_rn(a,  __shfl_xor(a, 2, 16));
            float h  = __fadd_rn(b2, __shfl_xor(b2, 4, 16));
            float tot = __fadd_rn(h, __shfl_xor(h, 8, 16));   // h0 + h1, own-first
            if (lane == 0) esq[k] = tot;
        }
    } else {
        __shared__ float tb[32][72];
        int blk = blockIdx.x - 512;
        int tt = blk & 31, cc = (blk >> 5) & 7, b = blk >> 8;
        int c0 = cc << 5, t0 = tt << 6;
        {
            int c_l = tid >> 3, t8 = (tid & 7) << 3;
            const float* src = x + (size_t)b * DIM * TLEN + (size_t)(c0 + c_l) * TLEN + t0 + t8;
            float4 v0 = *reinterpret_cast<const float4*>(src);
            float4 v1 = *reinterpret_cast<const float4*>(src + 4);
            tb[c_l][t8 + 0] = v0.x; tb[c_l][t8 + 1] = v0.y; tb[c_l][t8 + 2] = v0.z; tb[c_l][t8 + 3] = v0.w;
            tb[c_l][t8 + 4] = v1.x; tb[c_l][t8 + 5] = v1.y; tb[c_l][t8 + 6] = v1.z; tb[c_l][t8 + 7] = v1.w;
        }
        __syncthreads();
        {
            int cp = tid & 3, m_l = tid >> 2;
            size_t m = (size_t)b * TLEN + t0 + m_l;
            alignas(16) __hip_bfloat16 h8[8];
#pragma unroll
            for (int j = 0; j < 8; ++j)
                h8[j] = __float2bfloat16(tb[(cp << 3) + j][m_l]);
            *reinterpret_cast<int4*>(Xhi + m * DIM + c0 + (cp << 3)) = *reinterpret_cast<int4*>(h8);
        }
    }
}

// ---- Phase A: R8-proven loop (128x128 tile, BK=64, global_load_lds with
// pre-swizzled source, conflict-free, coalesced tb-major amax/mask output)
// + T1 XCD-aware work swizzle (bijective for nwg=4096).
__global__ __launch_bounds__(256, 4) void mfma_dist_kernel(const __hip_bfloat16* __restrict__ Xhi,
                                                           const __hip_bfloat16* __restrict__ Ehi,
                                                           unsigned* __restrict__ amax_g,
                                                           unsigned long long* __restrict__ mask_g) {
    __shared__ __hip_bfloat16 Ah[128 * 64];   // 16KB, x rows, swizzled layout
    __shared__ __hip_bfloat16 Bh[128 * 64];   // 16KB, codebook rows, swizzled

    int blk = (int)blockIdx.x;
    blk = (blk & 7) * 512 + (blk >> 3);        // T1 XCD swizzle
    int nt = blk & 15, mt = blk >> 4;
    int m0 = mt << 7, n0 = nt << 7;
    int tid = threadIdx.x;
    int w = tid >> 6, lane = tid & 63;
    int q = lane >> 4, c = lane & 15;
    int mhalf = w >> 1, nhalf = w & 1;

    int srow = lane >> 3;                      // 0..7 within chunk
    int scol = ((lane & 7) ^ srow) << 3;       // pre-swizzled source col (elems)
    const __hip_bfloat16* gA = Xhi + (size_t)(m0 + (w << 5) + srow) * DIM + scol;
    const __hip_bfloat16* gB = Ehi + (size_t)(n0 + (w << 5) + srow) * DIM + scol;

    f32x4 acc[4][4];   // [ci (code subtile)][mi (x-row subtile)]
#pragma unroll
    for (int ci = 0; ci < 4; ++ci)
#pragma unroll
        for (int mi = 0; mi < 4; ++mi) acc[ci][mi] = (f32x4){0.f, 0.f, 0.f, 0.f};

    const char* AhB = reinterpret_cast<const char*>(Ah);
    const char* BhB = reinterpret_cast<const char*>(Bh);
    int swzc = (c & 7) << 4;                   // read-side XOR

    for (int kk = 0; kk < DIM; kk += 64) {
#pragma unroll
        for (int j = 0; j < 4; ++j)
            __builtin_amdgcn_global_load_lds(
                (const __attribute__((address_space(1))) unsigned int*)(gA + (size_t)(j << 3) * DIM + kk),
                (__attribute__((address_space(3))) unsigned int*)(&Ah[((w << 2) + j) << 9]),
                16, 0, 0);
#pragma unroll
        for (int j = 0; j < 4; ++j)
            __builtin_amdgcn_global_load_lds(
                (const __attribute__((address_space(1))) unsigned int*)(gB + (size_t)(j << 3) * DIM + kk),
                (__attribute__((address_space(3))) unsigned int*)(&Bh[((w << 2) + j) << 9]),
                16, 0, 0);
        __syncthreads();
#pragma unroll
        for (int kh = 0; kh < 2; ++kh) {
            int swz = ((kh << 6) | (q << 4)) ^ swzc;
            bf16x8 xf[4], cf[4];
#pragma unroll
            for (int mi = 0; mi < 4; ++mi) {
                int row = (mhalf << 6) + (mi << 4) + c;
                xf[mi] = *reinterpret_cast<const bf16x8*>(AhB + (row << 7) + swz);
            }
#pragma unroll
            for (int ci = 0; ci < 4; ++ci) {
                int row = (nhalf << 6) + (ci << 4) + c;
                cf[ci] = *reinterpret_cast<const bf16x8*>(BhB + (row << 7) + swz);
            }
#pragma unroll
            for (int ci = 0; ci < 4; ++ci)
#pragma unroll
                for (int mi = 0; mi < 4; ++mi)
                    acc[ci][mi] = __builtin_amdgcn_mfma_f32_16x16x32_bf16(cf[ci], xf[mi], acc[ci][mi], 0, 0, 0);
        }
        __syncthreads();
    }

    int tb = (nt << 1) | nhalf;
#pragma unroll
    for (int mi = 0; mi < 4; ++mi) {
        float a16[16];
#pragma unroll
        for (int ci = 0; ci < 4; ++ci)
#pragma unroll
            for (int reg = 0; reg < 4; ++reg)
                a16[ci * 4 + reg] = acc[ci][mi][reg];
        float m01 = fmaxf(fmaxf(a16[0], a16[1]), fmaxf(a16[2], a16[3]));
        float m23 = fmaxf(fmaxf(a16[4], a16[5]), fmaxf(a16[6], a16[7]));
        float m45 = fmaxf(fmaxf(a16[8], a16[9]), fmaxf(a16[10], a16[11]));
        float m67 = fmaxf(fmaxf(a16[12], a16[13]), fmaxf(a16[14], a16[15]));
        float amax = fmaxf(fmaxf(m01, m23), fmaxf(m45, m67));
        amax = fmaxf(amax, __shfl_xor(amax, 16, 64));
        amax = fmaxf(amax, __shfl_xor(amax, 32, 64));
        float thrw = amax - AMARGIN;
        unsigned long long bits = 0;
#pragma unroll
        for (int v = 0; v < 16; ++v)
            if (a16[v] >= thrw)
                bits |= 1ULL << (((v >> 2) << 4) + (q << 2) + (v & 3));
        bits |= (unsigned long long)__shfl_xor((long long)bits, 16, 64);
        bits |= (unsigned long long)__shfl_xor((long long)bits, 32, 64);
        if (q == 0) {
            int m = m0 + (mhalf << 6) + (mi << 4) + c;
            amax_g[(size_t)tb * NROWS + m] = encf(amax);
            mask_g[(size_t)tb * NROWS + m] = bits;
        }
    }
}

// ---- Phase B (fused): retrospective qualification + exact recheck + STE
// output + idx + per-block double loss partial. No device-scope sync; the
// 1024 padded partials are reduced by the tiny finalize_d kernel.
__global__ __launch_bounds__(256) void recheck_out_kernel(const float* __restrict__ x,
                                                          const float* __restrict__ cb,
                                                          const float* __restrict__ esq,
                                                          const unsigned* __restrict__ amax_g,
                                                          const unsigned long long* __restrict__ mask_g,
                                                          float* __restrict__ out,
                                                          double* __restrict__ bsum) {
    __shared__ float xT[DIM * 33];      // 33.8 KB
    __shared__ float qT[DIM * 33];      // 33.8 KB
    __shared__ int clist[32][CCAP];
    __shared__ int ccnt[32];
    __shared__ int bidx[32];
    __shared__ double dsum[4];

    int tid = threadIdx.x;
    int blk = blockIdx.x;               // 1024 blocks, 32 rows each
    int b = blk >> 6, t0 = (blk & 63) << 5;
    const float* xb = x + (size_t)b * DIM * TLEN + t0;

    if (tid < 32) ccnt[tid] = 0;
    {   // coalesced staging: 8 c-rows x 32 t per iter
        int tl = tid & 31, c8 = tid >> 5;
        for (int cc = 0; cc < 32; ++cc) {
            int c = (cc << 3) + c8;
            xT[c * 33 + tl] = xb[(size_t)c * TLEN + tl];
        }
    }
    __syncthreads();

    int g = tid >> 3, l3 = tid & 7;     // group g handles row t0+g
    int m = (b << 11) + t0 + g;

    // xs: np pairwise chain, bit-exact (lane l3 owns accumulator r[l3])
    float h[2];
#pragma unroll
    for (int half = 0; half < 2; ++half) {
        int c0 = half * 128;
        float r = sq_rn(xT[(c0 + l3) * 33 + g]);
        for (int i = 8; i < 128; i += 8)
            r = __fadd_rn(r, sq_rn(xT[(c0 + i + l3) * 33 + g]));
        float a = __fadd_rn(r, __shfl_xor(r, 1, 8));
        float bb = __fadd_rn(a, __shfl_xor(a, 2, 8));
        h[half] = __fadd_rn(bb, __shfl_xor(bb, 4, 8));
    }
    float xs = __fadd_rn(h[0], h[1]);

    // global max over 32 tiles (encoded u32 preserves float order)
    unsigned am4[4];
    unsigned ge = 0;
#pragma unroll
    for (int j = 0; j < 4; ++j) {
        am4[j] = amax_g[(size_t)(l3 * 4 + j) * NROWS + m];
        ge = max(ge, am4[j]);
    }
    for (int off = 1; off < 8; off <<= 1)
        ge = max(ge, (unsigned)__shfl_xor((int)ge, off, 8));
    float thr = decf(ge) - AMARGIN;

    // expand qualifying tiles
#pragma unroll
    for (int j = 0; j < 4; ++j) {
        if (decf(am4[j]) >= thr) {
            unsigned long long bits = mask_g[(size_t)(l3 * 4 + j) * NROWS + m];
            while (bits) {
                int p = __ffsll((long long)bits) - 1; bits &= bits - 1;
                int pos = atomicAdd(&ccnt[g], 1);
                if (pos < CCAP) clist[g][pos] = (l3 * 4 + j) * 64 + p;
            }
        }
    }
    __syncthreads();

    int cnt = ccnt[g];
    float bd = 3.4e38f; int bi = 0x7fffffff;

    if (cnt <= CCAP) {
        for (int j = l3; j < cnt; j += 8) {
            int n = clist[g][j];
            const float* crow = cb + (size_t)n * DIM;
            float d = 0.f;
            for (int k = 0; k < DIM; k += 4) {     // ascending-k fmaf chain == np mm
                float4 cv = *reinterpret_cast<const float4*>(crow + k);
                d = fmaf(xT[(k + 0) * 33 + g], cv.x, d);
                d = fmaf(xT[(k + 1) * 33 + g], cv.y, d);
                d = fmaf(xT[(k + 2) * 33 + g], cv.z, d);
                d = fmaf(xT[(k + 3) * 33 + g], cv.w, d);
            }
            float d2 = __fadd_rn(__fadd_rn(xs, -2.0f * d), esq[n]);
            if (d2 < bd || (d2 == bd && n < bi)) { bd = d2; bi = n; }
        }
    } else {
        // overflow fallback: exact full scan (same formula, any order is fine)
        for (int n = l3; n < KCODES; n += 8) {
            const float* crow = cb + (size_t)n * DIM;
            float d = 0.f;
            for (int k = 0; k < DIM; k += 4) {
                float4 cv = *reinterpret_cast<const float4*>(crow + k);
                d = fmaf(xT[(k + 0) * 33 + g], cv.x, d);
                d = fmaf(xT[(k + 1) * 33 + g], cv.y, d);
                d = fmaf(xT[(k + 2) * 33 + g], cv.z, d);
                d = fmaf(xT[(k + 3) * 33 + g], cv.w, d);
            }
            float d2 = __fadd_rn(__fadd_rn(xs, -2.0f * d), esq[n]);
            if (d2 < bd || (d2 == bd && n < bi)) { bd = d2; bi = n; }
        }
    }
    for (int off = 1; off < 8; off <<= 1) {
        float od = __shfl_xor(bd, off, 8);
        int   oi = __shfl_xor(bi, off, 8);
        if (od < bd || (od == bd && oi < bi)) { bd = od; bi = oi; }
    }
    if (l3 == 0) {
        int idx = bi & 2047;
        bidx[g] = idx;
        out[(size_t)IDX_OFF + m] = (float)idx;
    }
    __syncthreads();

    // q-fetch: group g reads cb[bidx[g]] row coalesced (1KB contiguous) -> qT
    {
        int idx = bidx[g];
        const float* crow = cb + (size_t)idx * DIM + (l3 << 5);
#pragma unroll
        for (int j = 0; j < 8; ++j) {
            float4 v = *reinterpret_cast<const float4*>(crow + (j << 2));
            int c = (l3 << 5) + (j << 2);
            qT[(c + 0) * 33 + g] = v.x;
            qT[(c + 1) * 33 + g] = v.y;
            qT[(c + 2) * 33 + g] = v.z;
            qT[(c + 3) * 33 + g] = v.w;
        }
    }
    __syncthreads();

    // out-write + loss: t fastest (coalesced 128B segments), EXACT same fp ops
    // as the proven gather (diff = q - x; o = x + diff; s = diff*diff).
    {
        int tl = tid & 31, cbase = tid >> 5;
        float* ob = out + (size_t)b * DIM * TLEN + t0;
        double ds = 0.0;
        for (int cc = 0; cc < 32; ++cc) {
            int c = (cc << 3) + cbase;
            float xv = xT[c * 33 + tl];
            float qv = qT[c * 33 + tl];
            float diff = __fsub_rn(qv, xv);
            ob[(size_t)c * TLEN + tl] = __fadd_rn(xv, diff);
            ds += (double)__fmul_rn(diff, diff);
        }
        for (int off = 32; off > 0; off >>= 1) ds += __shfl_down(ds, off, 64);
        int lane = tid & 63, wid = tid >> 6;
        if (lane == 0) dsum[wid] = ds;
    }
    __syncthreads();
    if (tid == 0)
        bsum[(size_t)blk * 8] = (dsum[0] + dsum[1]) + (dsum[2] + dsum[3]);  // 64B slot
}

// ---- tiny final reduction: 1024 padded doubles -> means
__global__ __launch_bounds__(256) void finalize_d_kernel(const double* __restrict__ bsum,
                                                         float* __restrict__ out) {
    __shared__ double dsum[4];
    int tid = threadIdx.x;
    double s2 = bsum[(size_t)tid * 8] + bsum[(size_t)(tid + 256) * 8]
              + bsum[(size_t)(tid + 512) * 8] + bsum[(size_t)(tid + 768) * 8];
    for (int off = 32; off > 0; off >>= 1) s2 += __shfl_down(s2, off, 64);
    int lane = tid & 63, wid = tid >> 6;
    if (lane == 0) dsum[wid] = s2;
    __syncthreads();
    if (tid == 0) {
        double total = (dsum[0] + dsum[1]) + (dsum[2] + dsum[3]);
        float mean = (float)(total / (double)NELEM);
        out[LOSS_OFF] = mean;
        out[LOSS_OFF + 1] = 0.25f * mean;
    }
}

// ======== fallback path (R5): used only if ws_size is too small ========
__global__ __launch_bounds__(256) void init_keys_kernel(unsigned long long* __restrict__ keys) {
    keys[blockIdx.x * 256 + threadIdx.x] = ~0ULL;
}

__global__ __launch_bounds__(256, 4) void dist_kernel(const float* __restrict__ x,
                                                      const float* __restrict__ cb,
                                                      const float* __restrict__ xsq,
                                                      const float* __restrict__ esq,
                                                      unsigned long long* __restrict__ keys) {
    __shared__ float As[16][128];
    __shared__ float Bs[16][132];
    int blk = blockIdx.x;
    int nt = blk & 15, mt = blk >> 4;
    int m0 = mt << 7;
    int b = m0 >> 11, t0 = m0 & (TLEN - 1);
    int n0 = nt << 7;
    int tid = threadIdx.x;
    int tm = tid >> 4, tn = tid & 15;
    const float* xbase = x + (size_t)b * DIM * TLEN + t0;
    float acc[8][8] = {};
    for (int kk = 0; kk < DIM; kk += 16) {
#pragma unroll
        for (int h = 0; h < 2; ++h) {
            int qq = tid + (h << 8);
            int k = qq >> 5, mq = (qq & 31) << 2;
            float4 v = *reinterpret_cast<const float4*>(xbase + (size_t)(kk + k) * TLEN + mq);
            *reinterpret_cast<float4*>(&As[k][mq]) = v;
        }
#pragma unroll
        for (int h = 0; h < 2; ++h) {
            int qq = tid + (h << 8);
            int nr = qq >> 2, kc = (qq & 3) << 2;
            float4 v = *reinterpret_cast<const float4*>(cb + (size_t)(n0 + nr) * DIM + kk + kc);
            Bs[kc + 0][nr] = v.x; Bs[kc + 1][nr] = v.y;
            Bs[kc + 2][nr] = v.z; Bs[kc + 3][nr] = v.w;
        }
        __syncthreads();
#pragma unroll
        for (int k = 0; k < 16; ++k) {
            float4 a0 = *reinterpret_cast<const float4*>(&As[k][tm << 2]);
            float4 a1 = *reinterpret_cast<const float4*>(&As[k][64 + (tm << 2)]);
            float4 b0 = *reinterpret_cast<const float4*>(&Bs[k][tn << 2]);
            float4 b1 = *reinterpret_cast<const float4*>(&Bs[k][64 + (tn << 2)]);
            float am[8] = {a0.x, a0.y, a0.z, a0.w, a1.x, a1.y, a1.z, a1.w};
            float bn[8] = {b0.x, b0.y, b0.z, b0.w, b1.x, b1.y, b1.z, b1.w};
#pragma unroll
            for (int mi = 0; mi < 8; ++mi)
#pragma unroll
                for (int ni = 0; ni < 8; ++ni)
                    acc[mi][ni] = fmaf(am[mi], bn[ni], acc[mi][ni]);
        }
        __syncthreads();
    }
    int cn[8]; float es[8];
#pragma unroll
    for (int ni = 0; ni < 8; ++ni) {
        cn[ni] = n0 + ((ni < 4) ? (tn << 2) + ni : 60 + (tn << 2) + ni);
        es[ni] = esq[cn[ni]];
    }
#pragma unroll
    for (int mi = 0; mi < 8; ++mi) {
        int m = m0 + ((mi < 4) ? (tm << 2) + mi : 60 + (tm << 2) + mi);
        float xs = xsq[m];
        float bd = 3.4e38f;
        int bi = 0x7fffffff;
#pragma unroll
        for (int ni = 0; ni < 8; ++ni) {
            float d2 = __fadd_rn(__fadd_rn(xs, -2.0f * acc[mi][ni]), es[ni]);
            if (d2 < bd) { bd = d2; bi = cn[ni]; }
        }
        for (int off = 1; off < 16; off <<= 1) {
            float od = __shfl_xor(bd, off, 16);
            int oi = __shfl_xor(bi, off, 16);
            if (od < bd || (od == bd && oi < bi)) { bd = od; bi = oi; }
        }
        if (tn == 0) {
            unsigned long long key =
                ((unsigned long long)__float_as_uint(bd) << 32) | (unsigned)(bi & 2047);
            atomicMin(&keys[m], key);
        }
    }
}

__global__ __launch_bounds__(256) void gather_kernel(const float* __restrict__ x,
                                                     const float* __restrict__ cb,
                                                     const unsigned long long* __restrict__ keys,
                                                     float* __restrict__ out,
                                                     float* __restrict__ bsum) {
    int tid = threadIdx.x;
    int blk = blockIdx.x;               // 4096 = 16 b x 8 tc x 32 c8
    int c8 = blk & 31, tc = (blk >> 5) & 7, b = blk >> 8;
    int c0 = c8 << 3;
    int t = (tc << 8) + tid;
    int m = (b << 11) + t;
    unsigned idx = (unsigned)(keys[m]) & 2047u;
    const float* crow = cb + (size_t)idx * DIM + c0;
    float4 cv0 = *reinterpret_cast<const float4*>(crow);
    float4 cv1 = *reinterpret_cast<const float4*>(crow + 4);
    if (c8 == 0) out[(size_t)IDX_OFF + m] = (float)idx;

    float qv[8] = {cv0.x, cv0.y, cv0.z, cv0.w, cv1.x, cv1.y, cv1.z, cv1.w};
    __shared__ float wsum[4][8];
    int lane = tid & 63, wid = tid >> 6;
    float sv[8];
#pragma unroll
    for (int cc = 0; cc < 8; ++cc) {
        size_t e = (size_t)b * (DIM * TLEN) + (size_t)(c0 + cc) * TLEN + t;
        float xv = x[e];
        float diff = __fsub_rn(qv[cc], xv);
        out[e] = __fadd_rn(xv, diff);
        float s = __fmul_rn(diff, diff);
        for (int off = 32; off > 0; off >>= 1) s += __shfl_down(s, off, 64);
        sv[cc] = s;
    }
    if (lane == 0) {
#pragma unroll
        for (int cc = 0; cc < 8; ++cc) wsum[wid][cc] = sv[cc];
    }
    __syncthreads();
    if (tid == 0) {
#pragma unroll
        for (int cc = 0; cc < 8; ++cc)
            bsum[(b << 11) + ((c0 + cc) << 3) + tc] =
                ((wsum[0][cc] + wsum[1][cc]) + (wsum[2][cc] + wsum[3][cc]));
    }
}

__global__ __launch_bounds__(1024) void finalize_kernel(const float* __restrict__ bsum,
                                                        float* __restrict__ out) {
    double s = 0.0;
    for (int i = threadIdx.x; i < 32768; i += 1024) s += (double)bsum[i];
    for (int off = 32; off > 0; off >>= 1) s += __shfl_down(s, off, 64);
    __shared__ double wsum[16];
    int lane = threadIdx.x & 63, wid = threadIdx.x >> 6;
    if (lane == 0) wsum[wid] = s;
    __syncthreads();
    if (threadIdx.x == 0) {
        double total = 0.0;
        for (int ww = 0; ww < 16; ++ww) total += wsum[ww];
        float mean = (float)(total / (double)NELEM);
        out[LOSS_OFF] = mean;
        out[LOSS_OFF + 1] = 0.25f * mean;
    }
}
// ======== end fallback ========

extern "C" void kernel_launch(void* const* d_in, const int* in_sizes, int n_in,
                              void* d_out, int out_size, void* d_ws, size_t ws_size,
                              hipStream_t stream) {
    const float* x  = (const float*)d_in[0];
    const float* cb = (const float*)d_in[1];
    float* out = (float*)d_out;
    char* ws = (char*)d_ws;
    float* xsq = (float*)(ws + OFF_XSQ);
    float* esq = (float*)(ws + OFF_ESQ);

    if (ws_size >= WS_NEED) {
        __hip_bfloat16* Ehi = (__hip_bfloat16*)(ws + OFF_EHI);
        __hip_bfloat16* Xhi = (__hip_bfloat16*)(ws + OFF_XHI);
        unsigned* amax_g = (unsigned*)(ws + OFF_AMAX);
        unsigned long long* mask_g = (unsigned long long*)(ws + OFF_MASK);
        double* bsum_d = (double*)(ws + OFF_BSUM);
        prep_kernel<<<512 + NB * 8 * 32, 256, 0, stream>>>(cb, x, Ehi, esq, Xhi);
        mfma_dist_kernel<<<(NROWS / 128) * (KCODES / 128), 256, 0, stream>>>(
            Xhi, Ehi, amax_g, mask_g);
        recheck_out_kernel<<<NROWS / 32, 256, 0, stream>>>(
            x, cb, esq, amax_g, mask_g, out, bsum_d);
        finalize_d_kernel<<<1, 256, 0, stream>>>(bsum_d, out);
    } else {
        unsigned long long* keys = (unsigned long long*)(ws + OFF_KEYS);
        float* bsum = (float*)(ws + OFF_BSUM);
        esq_kernel<<<KCODES / 256, 256, 0, stream>>>(cb, esq);
        xsq_kernel<<<NROWS / 256, 256, 0, stream>>>(x, xsq);
        init_keys_kernel<<<NROWS / 256, 256, 0, stream>>>(keys);
        dist_kernel<<<(NROWS / 128) * (KCODES / 128), 256, 0, stream>>>(x, cb, xsq, esq, keys);
        gather_kernel<<<(NB * 8 * 32), 256, 0, stream>>>(x, cb, keys, out, bsum);
        finalize_kernel<<<1, 1024, 0, stream>>>(bsum, out);
    }
}

// Round 12
// 177.845 us; speedup vs baseline: 1.2039x; 1.0415x over previous
//
#include <hip/hip_runtime.h>
#include <hip/hip_bf16.h>

// Problem constants
#define KCODES 2048
#define DIM 256
#define TLEN 2048
#define NB 16
#define NROWS (NB * TLEN)          // 32768 rows (b*t)
#define NELEM (NB * DIM * TLEN)    // 8388608 elements of x / quant
#define LOSS_OFF NELEM
#define IDX_OFF (NELEM + 2)

// Margin in the a = (bf16 dot) domain (R5-R8/R11 proven, absmax 0.0 each time).
#define AMARGIN 1.8e-3f

// Candidate list capacity per row (retrospective global-max qualification,
// E[#cands] ~ 3-10). Overflow -> exact full scan.
#define CCAP 48

// ws layout (bytes) — total ~29.5 MB
#define OFF_XSQ   0ull                       // 131072 (fallback path only)
#define OFF_ESQ   131072ull                  // 8192
#define OFF_KEYS  139264ull                  // keys (fallback path only)
#define OFF_BSUM  401408ull                  // 2048 * 64B padded doubles (main)
#define OFF_EHI   532480ull                  // 1048576
#define OFF_XHI   1581056ull                 // 16777216
#define OFF_AMAX  18358272ull                // 32*32768*4  = 4194304
#define OFF_MASK  22552576ull                // 32*32768*8  = 8388608
#define WS_NEED   30941184ull

typedef __bf16 bf16x8 __attribute__((ext_vector_type(8)));
typedef float  f32x4  __attribute__((ext_vector_type(4)));

__device__ __forceinline__ float sq_rn(float v) { return __fmul_rn(v, v); }

// order-preserving float<->u32 encoding (uint order == float order)
__device__ __forceinline__ unsigned encf(float f) {
    unsigned u = __float_as_uint(f);
    return (u & 0x80000000u) ? ~u : (u | 0x80000000u);
}
__device__ __forceinline__ float decf(unsigned k) {
    return __uint_as_float((k & 0x80000000u) ? (k & 0x7FFFFFFFu) : ~k);
}

// ---- x_sq: numpy pairwise sum (fallback path only)
__global__ __launch_bounds__(256) void xsq_kernel(const float* __restrict__ x,
                                                  float* __restrict__ xsq) {
    int m = blockIdx.x * 256 + threadIdx.x;
    int b = m >> 11, t = m & (TLEN - 1);
    const float* p = x + (size_t)b * DIM * TLEN + t;
    float h[2];
#pragma unroll
    for (int half = 0; half < 2; ++half) {
        int c0 = half * 128;
        float r[8];
#pragma unroll
        for (int j = 0; j < 8; ++j) r[j] = sq_rn(p[(size_t)(c0 + j) * TLEN]);
        for (int i = 8; i < 128; i += 8) {
#pragma unroll
            for (int j = 0; j < 8; ++j)
                r[j] = __fadd_rn(r[j], sq_rn(p[(size_t)(c0 + i + j) * TLEN]));
        }
        h[half] = __fadd_rn(__fadd_rn(__fadd_rn(r[0], r[1]), __fadd_rn(r[2], r[3])),
                            __fadd_rn(__fadd_rn(r[4], r[5]), __fadd_rn(r[6], r[7])));
    }
    xsq[m] = __fadd_rn(h[0], h[1]);
}

// ---- esq standalone (fallback path only)
__global__ __launch_bounds__(256) void esq_kernel(const float* __restrict__ cb,
                                                  float* __restrict__ esq) {
    int k = blockIdx.x * 256 + threadIdx.x;
    const float* p = cb + (size_t)k * DIM;
    float h[2];
#pragma unroll
    for (int half = 0; half < 2; ++half) {
        int c0 = half * 128;
        float r[8];
#pragma unroll
        for (int j = 0; j < 8; ++j) r[j] = sq_rn(p[c0 + j]);
        for (int i = 8; i < 128; i += 8) {
#pragma unroll
            for (int j = 0; j < 8; ++j)
                r[j] = __fadd_rn(r[j], sq_rn(p[c0 + i + j]));
        }
        h[half] = __fadd_rn(__fadd_rn(__fadd_rn(r[0], r[1]), __fadd_rn(r[2], r[3])),
                            __fadd_rn(__fadd_rn(r[4], r[5]), __fadd_rn(r[6], r[7])));
    }
    esq[k] = __fadd_rn(h[0], h[1]);
}

// ---- fused prep: blocks [0,512) do cb -> Ehi + esq (exact np chain, proven);
// blocks [512, 4608) do x -> Xhi transpose+round (R0-proven).
__global__ __launch_bounds__(256) void prep_kernel(const float* __restrict__ cb,
                                                   const float* __restrict__ x,
                                                   __hip_bfloat16* __restrict__ Ehi,
                                                   float* __restrict__ esq,
                                                   __hip_bfloat16* __restrict__ Xhi) {
    int tid = threadIdx.x;
    if (blockIdx.x < 512) {
        int w = tid >> 6, lane = tid & 63;
        int k = ((int)blockIdx.x << 2) + w;          // code row
        const float* p = cb + (size_t)k * DIM;

        float4 v = *reinterpret_cast<const float4*>(p + (lane << 2));
        alignas(8) __hip_bfloat16 h4[4];
        h4[0] = __float2bfloat16(v.x); h4[1] = __float2bfloat16(v.y);
        h4[2] = __float2bfloat16(v.z); h4[3] = __float2bfloat16(v.w);
        *reinterpret_cast<int2*>(Ehi + (size_t)k * DIM + (lane << 2)) = *reinterpret_cast<int2*>(h4);

        if (lane < 16) {
            int c0 = (lane >> 3) << 7, j = lane & 7;
            float r = sq_rn(p[c0 + j]);
            for (int i = 8; i < 128; i += 8)
                r = __fadd_rn(r, sq_rn(p[c0 + i + j]));
            float a  = __fadd_rn(r,  __shfl_xor(r, 1, 16));
            float b2 = __fadd_rn(a,  __shfl_xor(a, 2, 16));
            float h  = __fadd_rn(b2, __shfl_xor(b2, 4, 16));
            float tot = __fadd_rn(h, __shfl_xor(h, 8, 16));   // h0 + h1, own-first
            if (lane == 0) esq[k] = tot;
        }
    } else {
        __shared__ float tb[32][72];
        int blk = blockIdx.x - 512;
        int tt = blk & 31, cc = (blk >> 5) & 7, b = blk >> 8;
        int c0 = cc << 5, t0 = tt << 6;
        {
            int c_l = tid >> 3, t8 = (tid & 7) << 3;
            const float* src = x + (size_t)b * DIM * TLEN + (size_t)(c0 + c_l) * TLEN + t0 + t8;
            float4 v0 = *reinterpret_cast<const float4*>(src);
            float4 v1 = *reinterpret_cast<const float4*>(src + 4);
            tb[c_l][t8 + 0] = v0.x; tb[c_l][t8 + 1] = v0.y; tb[c_l][t8 + 2] = v0.z; tb[c_l][t8 + 3] = v0.w;
            tb[c_l][t8 + 4] = v1.x; tb[c_l][t8 + 5] = v1.y; tb[c_l][t8 + 6] = v1.z; tb[c_l][t8 + 7] = v1.w;
        }
        __syncthreads();
        {
            int cp = tid & 3, m_l = tid >> 2;
            size_t m = (size_t)b * TLEN + t0 + m_l;
            alignas(16) __hip_bfloat16 h8[8];
#pragma unroll
            for (int j = 0; j < 8; ++j)
                h8[j] = __float2bfloat16(tb[(cp << 3) + j][m_l]);
            *reinterpret_cast<int4*>(Xhi + m * DIM + c0 + (cp << 3)) = *reinterpret_cast<int4*>(h8);
        }
    }
}

// ---- Phase A: R8-proven loop (128x128 tile, BK=64, global_load_lds with
// pre-swizzled source, conflict-free, coalesced tb-major amax/mask output)
// + T1 XCD-aware work swizzle (bijective for nwg=4096; R11: FETCH 66->13 MB).
__global__ __launch_bounds__(256, 4) void mfma_dist_kernel(const __hip_bfloat16* __restrict__ Xhi,
                                                           const __hip_bfloat16* __restrict__ Ehi,
                                                           unsigned* __restrict__ amax_g,
                                                           unsigned long long* __restrict__ mask_g) {
    __shared__ __hip_bfloat16 Ah[128 * 64];   // 16KB, x rows, swizzled layout
    __shared__ __hip_bfloat16 Bh[128 * 64];   // 16KB, codebook rows, swizzled

    int blk = (int)blockIdx.x;
    blk = (blk & 7) * 512 + (blk >> 3);        // T1 XCD swizzle
    int nt = blk & 15, mt = blk >> 4;
    int m0 = mt << 7, n0 = nt << 7;
    int tid = threadIdx.x;
    int w = tid >> 6, lane = tid & 63;
    int q = lane >> 4, c = lane & 15;
    int mhalf = w >> 1, nhalf = w & 1;

    int srow = lane >> 3;                      // 0..7 within chunk
    int scol = ((lane & 7) ^ srow) << 3;       // pre-swizzled source col (elems)
    const __hip_bfloat16* gA = Xhi + (size_t)(m0 + (w << 5) + srow) * DIM + scol;
    const __hip_bfloat16* gB = Ehi + (size_t)(n0 + (w << 5) + srow) * DIM + scol;

    f32x4 acc[4][4];   // [ci (code subtile)][mi (x-row subtile)]
#pragma unroll
    for (int ci = 0; ci < 4; ++ci)
#pragma unroll
        for (int mi = 0; mi < 4; ++mi) acc[ci][mi] = (f32x4){0.f, 0.f, 0.f, 0.f};

    const char* AhB = reinterpret_cast<const char*>(Ah);
    const char* BhB = reinterpret_cast<const char*>(Bh);
    int swzc = (c & 7) << 4;                   // read-side XOR

    for (int kk = 0; kk < DIM; kk += 64) {
#pragma unroll
        for (int j = 0; j < 4; ++j)
            __builtin_amdgcn_global_load_lds(
                (const __attribute__((address_space(1))) unsigned int*)(gA + (size_t)(j << 3) * DIM + kk),
                (__attribute__((address_space(3))) unsigned int*)(&Ah[((w << 2) + j) << 9]),
                16, 0, 0);
#pragma unroll
        for (int j = 0; j < 4; ++j)
            __builtin_amdgcn_global_load_lds(
                (const __attribute__((address_space(1))) unsigned int*)(gB + (size_t)(j << 3) * DIM + kk),
                (__attribute__((address_space(3))) unsigned int*)(&Bh[((w << 2) + j) << 9]),
                16, 0, 0);
        __syncthreads();
#pragma unroll
        for (int kh = 0; kh < 2; ++kh) {
            int swz = ((kh << 6) | (q << 4)) ^ swzc;
            bf16x8 xf[4], cf[4];
#pragma unroll
            for (int mi = 0; mi < 4; ++mi) {
                int row = (mhalf << 6) + (mi << 4) + c;
                xf[mi] = *reinterpret_cast<const bf16x8*>(AhB + (row << 7) + swz);
            }
#pragma unroll
            for (int ci = 0; ci < 4; ++ci) {
                int row = (nhalf << 6) + (ci << 4) + c;
                cf[ci] = *reinterpret_cast<const bf16x8*>(BhB + (row << 7) + swz);
            }
#pragma unroll
            for (int ci = 0; ci < 4; ++ci)
#pragma unroll
                for (int mi = 0; mi < 4; ++mi)
                    acc[ci][mi] = __builtin_amdgcn_mfma_f32_16x16x32_bf16(cf[ci], xf[mi], acc[ci][mi], 0, 0, 0);
        }
        __syncthreads();
    }

    int tb = (nt << 1) | nhalf;
#pragma unroll
    for (int mi = 0; mi < 4; ++mi) {
        float a16[16];
#pragma unroll
        for (int ci = 0; ci < 4; ++ci)
#pragma unroll
            for (int reg = 0; reg < 4; ++reg)
                a16[ci * 4 + reg] = acc[ci][mi][reg];
        float m01 = fmaxf(fmaxf(a16[0], a16[1]), fmaxf(a16[2], a16[3]));
        float m23 = fmaxf(fmaxf(a16[4], a16[5]), fmaxf(a16[6], a16[7]));
        float m45 = fmaxf(fmaxf(a16[8], a16[9]), fmaxf(a16[10], a16[11]));
        float m67 = fmaxf(fmaxf(a16[12], a16[13]), fmaxf(a16[14], a16[15]));
        float amax = fmaxf(fmaxf(m01, m23), fmaxf(m45, m67));
        amax = fmaxf(amax, __shfl_xor(amax, 16, 64));
        amax = fmaxf(amax, __shfl_xor(amax, 32, 64));
        float thrw = amax - AMARGIN;
        unsigned long long bits = 0;
#pragma unroll
        for (int v = 0; v < 16; ++v)
            if (a16[v] >= thrw)
                bits |= 1ULL << (((v >> 2) << 4) + (q << 2) + (v & 3));
        bits |= (unsigned long long)__shfl_xor((long long)bits, 16, 64);
        bits |= (unsigned long long)__shfl_xor((long long)bits, 32, 64);
        if (q == 0) {
            int m = m0 + (mhalf << 6) + (mi << 4) + c;
            amax_g[(size_t)tb * NROWS + m] = encf(amax);
            mask_g[(size_t)tb * NROWS + m] = bits;
        }
    }
}

// ---- Phase B (fused, 16 rows/block): R11's proven structure at 2x occupancy.
// LDS 74->38 KB (xT/qT [256][17]) -> 4 blocks/CU; 16-lane row groups. xs chain
// split across lane halves stays bit-exact (IEEE fadd commutativity: butterfly
// lanes all hold the identical np pairwise sum). qT addressing is 2-way bank-
// aliased (free, m136) -> kills R11's 2.67M conflicts.
__global__ __launch_bounds__(256, 4) void recheck_out_kernel(const float* __restrict__ x,
                                                             const float* __restrict__ cb,
                                                             const float* __restrict__ esq,
                                                             const unsigned* __restrict__ amax_g,
                                                             const unsigned long long* __restrict__ mask_g,
                                                             float* __restrict__ out,
                                                             double* __restrict__ bsum) {
    __shared__ float xT[DIM * 17];      // 17.4 KB
    __shared__ float qT[DIM * 17];      // 17.4 KB
    __shared__ int clist[16][CCAP];     // 3 KB
    __shared__ int ccnt[16];
    __shared__ int bidx[16];
    __shared__ double dsum[4];

    int tid = threadIdx.x;
    int blk = blockIdx.x;               // 2048 blocks, 16 rows each
    int b = blk >> 7, t0 = (blk & 127) << 4;
    const float* xb = x + (size_t)b * DIM * TLEN + t0;

    if (tid < 16) ccnt[tid] = 0;
    {   // staging: 16 c-rows x 16 t per iter
        int tl = tid & 15, c16 = tid >> 4;
        for (int cc = 0; cc < 16; ++cc) {
            int c = (cc << 4) + c16;
            xT[c * 17 + tl] = xb[(size_t)c * TLEN + tl];
        }
    }
    __syncthreads();

    int g = tid >> 4, l4 = tid & 15;    // group g (16 lanes) handles row t0+g
    int m = (b << 11) + t0 + g;

    // xs: np pairwise chain. Lanes 0-7 accumulate half0's r[j], lanes 8-15
    // half1's; xor 1,2,4 builds each half's tree, xor 8 adds halves. All adds
    // commutative -> bit-identical to the proven sequential chain.
    float xs;
    {
        int half = l4 >> 3, j = l4 & 7;
        int c0 = half << 7;
        float r = sq_rn(xT[(c0 + j) * 17 + g]);
        for (int i = 8; i < 128; i += 8)
            r = __fadd_rn(r, sq_rn(xT[(c0 + i + j) * 17 + g]));
        float a  = __fadd_rn(r, __shfl_xor(r, 1, 16));
        float b2 = __fadd_rn(a, __shfl_xor(a, 2, 16));
        float hh = __fadd_rn(b2, __shfl_xor(b2, 4, 16));
        xs = __fadd_rn(hh, __shfl_xor(hh, 8, 16));
    }

    // global max over 32 tiles: 2 per lane, xor-reduce width 16
    unsigned am2[2];
    unsigned ge = 0;
#pragma unroll
    for (int j = 0; j < 2; ++j) {
        am2[j] = amax_g[(size_t)(l4 * 2 + j) * NROWS + m];
        ge = max(ge, am2[j]);
    }
    for (int off = 1; off < 16; off <<= 1)
        ge = max(ge, (unsigned)__shfl_xor((int)ge, off, 16));
    float thr = decf(ge) - AMARGIN;

    // expand qualifying tiles
#pragma unroll
    for (int j = 0; j < 2; ++j) {
        if (decf(am2[j]) >= thr) {
            unsigned long long bits = mask_g[(size_t)(l4 * 2 + j) * NROWS + m];
            while (bits) {
                int p = __ffsll((long long)bits) - 1; bits &= bits - 1;
                int pos = atomicAdd(&ccnt[g], 1);
                if (pos < CCAP) clist[g][pos] = (l4 * 2 + j) * 64 + p;
            }
        }
    }
    __syncthreads();

    int cnt = ccnt[g];
    float bd = 3.4e38f; int bi = 0x7fffffff;

    if (cnt <= CCAP) {
        for (int j = l4; j < cnt; j += 16) {
            int n = clist[g][j];
            const float* crow = cb + (size_t)n * DIM;
            float d = 0.f;
            for (int k = 0; k < DIM; k += 4) {     // ascending-k fmaf chain == np mm
                float4 cv = *reinterpret_cast<const float4*>(crow + k);
                d = fmaf(xT[(k + 0) * 17 + g], cv.x, d);
                d = fmaf(xT[(k + 1) * 17 + g], cv.y, d);
                d = fmaf(xT[(k + 2) * 17 + g], cv.z, d);
                d = fmaf(xT[(k + 3) * 17 + g], cv.w, d);
            }
            float d2 = __fadd_rn(__fadd_rn(xs, -2.0f * d), esq[n]);
            if (d2 < bd || (d2 == bd && n < bi)) { bd = d2; bi = n; }
        }
    } else {
        // overflow fallback: exact full scan (same formula, any order is fine)
        for (int n = l4; n < KCODES; n += 16) {
            const float* crow = cb + (size_t)n * DIM;
            float d = 0.f;
            for (int k = 0; k < DIM; k += 4) {
                float4 cv = *reinterpret_cast<const float4*>(crow + k);
                d = fmaf(xT[(k + 0) * 17 + g], cv.x, d);
                d = fmaf(xT[(k + 1) * 17 + g], cv.y, d);
                d = fmaf(xT[(k + 2) * 17 + g], cv.z, d);
                d = fmaf(xT[(k + 3) * 17 + g], cv.w, d);
            }
            float d2 = __fadd_rn(__fadd_rn(xs, -2.0f * d), esq[n]);
            if (d2 < bd || (d2 == bd && n < bi)) { bd = d2; bi = n; }
        }
    }
    for (int off = 1; off < 16; off <<= 1) {
        float od = __shfl_xor(bd, off, 16);
        int   oi = __shfl_xor(bi, off, 16);
        if (od < bd || (od == bd && oi < bi)) { bd = od; bi = oi; }
    }
    if (l4 == 0) {
        int idx = bi & 2047;
        bidx[g] = idx;
        out[(size_t)IDX_OFF + m] = (float)idx;
    }
    __syncthreads();

    // q-fetch: group g reads cb[bidx[g]] row coalesced (256B/group/pass) -> qT
    {
        int idx = bidx[g];
        const float* crow = cb + (size_t)idx * DIM;
#pragma unroll
        for (int p = 0; p < 4; ++p) {
            int c = (p << 6) + (l4 << 2);
            float4 v = *reinterpret_cast<const float4*>(crow + c);
            qT[(c + 0) * 17 + g] = v.x;
            qT[(c + 1) * 17 + g] = v.y;
            qT[(c + 2) * 17 + g] = v.z;
            qT[(c + 3) * 17 + g] = v.w;
        }
    }
    __syncthreads();

    // out-write + loss: t fastest (64B segments), EXACT same fp ops as the
    // proven gather (diff = q - x; o = x + diff; s = diff*diff).
    {
        int tl = tid & 15, cbase = tid >> 4;
        float* ob = out + (size_t)b * DIM * TLEN + t0;
        double ds = 0.0;
        for (int cc = 0; cc < 16; ++cc) {
            int c = (cc << 4) + cbase;
            float xv = xT[c * 17 + tl];
            float qv = qT[c * 17 + tl];
            float diff = __fsub_rn(qv, xv);
            ob[(size_t)c * TLEN + tl] = __fadd_rn(xv, diff);
            ds += (double)__fmul_rn(diff, diff);
        }
        for (int off = 32; off > 0; off >>= 1) ds += __shfl_down(ds, off, 64);
        int lane = tid & 63, wid = tid >> 6;
        if (lane == 0) dsum[wid] = ds;
    }
    __syncthreads();
    if (tid == 0)
        bsum[(size_t)blk * 8] = (dsum[0] + dsum[1]) + (dsum[2] + dsum[3]);  // 64B slot
}

// ---- tiny final reduction: 2048 padded doubles -> means
__global__ __launch_bounds__(256) void finalize_d_kernel(const double* __restrict__ bsum,
                                                         float* __restrict__ out) {
    __shared__ double dsum[4];
    int tid = threadIdx.x;
    double s2 = 0.0;
    for (int i = tid; i < 2048; i += 256) s2 += bsum[(size_t)i * 8];
    for (int off = 32; off > 0; off >>= 1) s2 += __shfl_down(s2, off, 64);
    int lane = tid & 63, wid = tid >> 6;
    if (lane == 0) dsum[wid] = s2;
    __syncthreads();
    if (tid == 0) {
        double total = (dsum[0] + dsum[1]) + (dsum[2] + dsum[3]);
        float mean = (float)(total / (double)NELEM);
        out[LOSS_OFF] = mean;
        out[LOSS_OFF + 1] = 0.25f * mean;
    }
}

// ======== fallback path (R5): used only if ws_size is too small ========
__global__ __launch_bounds__(256) void init_keys_kernel(unsigned long long* __restrict__ keys) {
    keys[blockIdx.x * 256 + threadIdx.x] = ~0ULL;
}

__global__ __launch_bounds__(256, 4) void dist_kernel(const float* __restrict__ x,
                                                      const float* __restrict__ cb,
                                                      const float* __restrict__ xsq,
                                                      const float* __restrict__ esq,
                                                      unsigned long long* __restrict__ keys) {
    __shared__ float As[16][128];
    __shared__ float Bs[16][132];
    int blk = blockIdx.x;
    int nt = blk & 15, mt = blk >> 4;
    int m0 = mt << 7;
    int b = m0 >> 11, t0 = m0 & (TLEN - 1);
    int n0 = nt << 7;
    int tid = threadIdx.x;
    int tm = tid >> 4, tn = tid & 15;
    const float* xbase = x + (size_t)b * DIM * TLEN + t0;
    float acc[8][8] = {};
    for (int kk = 0; kk < DIM; kk += 16) {
#pragma unroll
        for (int h = 0; h < 2; ++h) {
            int qq = tid + (h << 8);
            int k = qq >> 5, mq = (qq & 31) << 2;
            float4 v = *reinterpret_cast<const float4*>(xbase + (size_t)(kk + k) * TLEN + mq);
            *reinterpret_cast<float4*>(&As[k][mq]) = v;
        }
#pragma unroll
        for (int h = 0; h < 2; ++h) {
            int qq = tid + (h << 8);
            int nr = qq >> 2, kc = (qq & 3) << 2;
            float4 v = *reinterpret_cast<const float4*>(cb + (size_t)(n0 + nr) * DIM + kk + kc);
            Bs[kc + 0][nr] = v.x; Bs[kc + 1][nr] = v.y;
            Bs[kc + 2][nr] = v.z; Bs[kc + 3][nr] = v.w;
        }
        __syncthreads();
#pragma unroll
        for (int k = 0; k < 16; ++k) {
            float4 a0 = *reinterpret_cast<const float4*>(&As[k][tm << 2]);
            float4 a1 = *reinterpret_cast<const float4*>(&As[k][64 + (tm << 2)]);
            float4 b0 = *reinterpret_cast<const float4*>(&Bs[k][tn << 2]);
            float4 b1 = *reinterpret_cast<const float4*>(&Bs[k][64 + (tn << 2)]);
            float am[8] = {a0.x, a0.y, a0.z, a0.w, a1.x, a1.y, a1.z, a1.w};
            float bn[8] = {b0.x, b0.y, b0.z, b0.w, b1.x, b1.y, b1.z, b1.w};
#pragma unroll
            for (int mi = 0; mi < 8; ++mi)
#pragma unroll
                for (int ni = 0; ni < 8; ++ni)
                    acc[mi][ni] = fmaf(am[mi], bn[ni], acc[mi][ni]);
        }
        __syncthreads();
    }
    int cn[8]; float es[8];
#pragma unroll
    for (int ni = 0; ni < 8; ++ni) {
        cn[ni] = n0 + ((ni < 4) ? (tn << 2) + ni : 60 + (tn << 2) + ni);
        es[ni] = esq[cn[ni]];
    }
#pragma unroll
    for (int mi = 0; mi < 8; ++mi) {
        int m = m0 + ((mi < 4) ? (tm << 2) + mi : 60 + (tm << 2) + mi);
        float xs = xsq[m];
        float bd = 3.4e38f;
        int bi = 0x7fffffff;
#pragma unroll
        for (int ni = 0; ni < 8; ++ni) {
            float d2 = __fadd_rn(__fadd_rn(xs, -2.0f * acc[mi][ni]), es[ni]);
            if (d2 < bd) { bd = d2; bi = cn[ni]; }
        }
        for (int off = 1; off < 16; off <<= 1) {
            float od = __shfl_xor(bd, off, 16);
            int oi = __shfl_xor(bi, off, 16);
            if (od < bd || (od == bd && oi < bi)) { bd = od; bi = oi; }
        }
        if (tn == 0) {
            unsigned long long key =
                ((unsigned long long)__float_as_uint(bd) << 32) | (unsigned)(bi & 2047);
            atomicMin(&keys[m], key);
        }
    }
}

__global__ __launch_bounds__(256) void gather_kernel(const float* __restrict__ x,
                                                     const float* __restrict__ cb,
                                                     const unsigned long long* __restrict__ keys,
                                                     float* __restrict__ out,
                                                     float* __restrict__ bsum) {
    int tid = threadIdx.x;
    int blk = blockIdx.x;               // 4096 = 16 b x 8 tc x 32 c8
    int c8 = blk & 31, tc = (blk >> 5) & 7, b = blk >> 8;
    int c0 = c8 << 3;
    int t = (tc << 8) + tid;
    int m = (b << 11) + t;
    unsigned idx = (unsigned)(keys[m]) & 2047u;
    const float* crow = cb + (size_t)idx * DIM + c0;
    float4 cv0 = *reinterpret_cast<const float4*>(crow);
    float4 cv1 = *reinterpret_cast<const float4*>(crow + 4);
    if (c8 == 0) out[(size_t)IDX_OFF + m] = (float)idx;

    float qv[8] = {cv0.x, cv0.y, cv0.z, cv0.w, cv1.x, cv1.y, cv1.z, cv1.w};
    __shared__ float wsum[4][8];
    int lane = tid & 63, wid = tid >> 6;
    float sv[8];
#pragma unroll
    for (int cc = 0; cc < 8; ++cc) {
        size_t e = (size_t)b * (DIM * TLEN) + (size_t)(c0 + cc) * TLEN + t;
        float xv = x[e];
        float diff = __fsub_rn(qv[cc], xv);
        out[e] = __fadd_rn(xv, diff);
        float s = __fmul_rn(diff, diff);
        for (int off = 32; off > 0; off >>= 1) s += __shfl_down(s, off, 64);
        sv[cc] = s;
    }
    if (lane == 0) {
#pragma unroll
        for (int cc = 0; cc < 8; ++cc) wsum[wid][cc] = sv[cc];
    }
    __syncthreads();
    if (tid == 0) {
#pragma unroll
        for (int cc = 0; cc < 8; ++cc)
            bsum[(b << 11) + ((c0 + cc) << 3) + tc] =
                ((wsum[0][cc] + wsum[1][cc]) + (wsum[2][cc] + wsum[3][cc]));
    }
}

__global__ __launch_bounds__(1024) void finalize_kernel(const float* __restrict__ bsum,
                                                        float* __restrict__ out) {
    double s = 0.0;
    for (int i = threadIdx.x; i < 32768; i += 1024) s += (double)bsum[i];
    for (int off = 32; off > 0; off >>= 1) s += __shfl_down(s, off, 64);
    __shared__ double wsum[16];
    int lane = threadIdx.x & 63, wid = threadIdx.x >> 6;
    if (lane == 0) wsum[wid] = s;
    __syncthreads();
    if (threadIdx.x == 0) {
        double total = 0.0;
        for (int ww = 0; ww < 16; ++ww) total += wsum[ww];
        float mean = (float)(total / (double)NELEM);
        out[LOSS_OFF] = mean;
        out[LOSS_OFF + 1] = 0.25f * mean;
    }
}
// ======== end fallback ========

extern "C" void kernel_launch(void* const* d_in, const int* in_sizes, int n_in,
                              void* d_out, int out_size, void* d_ws, size_t ws_size,
                              hipStream_t stream) {
    const float* x  = (const float*)d_in[0];
    const float* cb = (const float*)d_in[1];
    float* out = (float*)d_out;
    char* ws = (char*)d_ws;
    float* xsq = (float*)(ws + OFF_XSQ);
    float* esq = (float*)(ws + OFF_ESQ);

    if (ws_size >= WS_NEED) {
        __hip_bfloat16* Ehi = (__hip_bfloat16*)(ws + OFF_EHI);
        __hip_bfloat16* Xhi = (__hip_bfloat16*)(ws + OFF_XHI);
        unsigned* amax_g = (unsigned*)(ws + OFF_AMAX);
        unsigned long long* mask_g = (unsigned long long*)(ws + OFF_MASK);
        double* bsum_d = (double*)(ws + OFF_BSUM);
        prep_kernel<<<512 + NB * 8 * 32, 256, 0, stream>>>(cb, x, Ehi, esq, Xhi);
        mfma_dist_kernel<<<(NROWS / 128) * (KCODES / 128), 256, 0, stream>>>(
            Xhi, Ehi, amax_g, mask_g);
        recheck_out_kernel<<<NROWS / 16, 256, 0, stream>>>(
            x, cb, esq, amax_g, mask_g, out, bsum_d);
        finalize_d_kernel<<<1, 256, 0, stream>>>(bsum_d, out);
    } else {
        unsigned long long* keys = (unsigned long long*)(ws + OFF_KEYS);
        float* bsum = (float*)(ws + OFF_BSUM);
        esq_kernel<<<KCODES / 256, 256, 0, stream>>>(cb, esq);
        xsq_kernel<<<NROWS / 256, 256, 0, stream>>>(x, xsq);
        init_keys_kernel<<<NROWS / 256, 256, 0, stream>>>(keys);
        dist_kernel<<<(NROWS / 128) * (KCODES / 128), 256, 0, stream>>>(x, cb, xsq, esq, keys);
        gather_kernel<<<(NB * 8 * 32), 256, 0, stream>>>(x, cb, keys, out, bsum);
        finalize_kernel<<<1, 1024, 0, stream>>>(bsum, out);
    }
}